// Round 10
// baseline (405.534 us; speedup 1.0000x reference)
//
#include <hip/hip_runtime.h>
#include <hip/hip_bf16.h>
#include <cstddef>
#include <cstdint>

// Problem dims
constexpr int Bv = 128;   // batch
constexpr int Sv = 256;   // src len
constexpr int Hv = 1024;  // hidden
constexpr int Ev = 512;   // embed
constexpr int Vv = 32000; // vocab

typedef __attribute__((ext_vector_type(4))) float f32x4;
typedef __attribute__((ext_vector_type(8))) short short8;

// f32x4 -> 4 packed bf16 (RNE), via v_cvt_pk_bf16_f32.
__device__ __forceinline__ uint2 cvt4(float4 v) {
  union { __hip_bfloat162 b; unsigned u; } lo, hi;
  lo.b = __float22bfloat162_rn(float2{v.x, v.y});
  hi.b = __float22bfloat162_rn(float2{v.z, v.w});
  uint2 r;
  r.x = lo.u;
  r.y = hi.u;
  return r;
}
__device__ __forceinline__ unsigned short cvt1(float x) {
  union { __hip_bfloat16 b; unsigned short u; } c;
  c.b = __float2bfloat16(x);
  return c.u;
}

__device__ __forceinline__ float sigm(float x) {
  return 1.f / (1.f + expf(-x));
}

// ---------------------------------------------------------------------------
// MFMA GEMM with split-K partials + optional fused tail-block epilogue.
//   Cp[z][m,n] = sum_{k in split z} A[m,k]*W[n,k]  (+bias on z==0)
// EPI=0: none (C is final when SPLIT==1; else consumer sums partials).
// EPI=1: LSTM pointwise. grid (128,2,SPLIT), N=4096. Counter per
//        (j-tile, m-tile) over 4 gates x SPLIT z = 4*SPLIT blocks; the last
//        arriver sums partials, applies gates, writes xh (h_out), xo (c_out)
//        using xc (c_prev).
// EPI=2: concat tanh. grid (32,2,SPLIT), N=1024. Counter per (x,y) over
//        SPLIT z; last arriver sums partials pairwise, tanh, writes xh (cat).
// Correctness: last-arriver pattern (no ordering assumption, no spin);
// release via ACQ_REL atomic after __threadfence, acquire on the same RMW.
// Sum order fixed by loop order -> deterministic, bit-identical to the
// previous separate lstm_pw / finish_cat kernels.
// ---------------------------------------------------------------------------
template <int BM, int BN, int BK, int SPLIT, int WTR, int GATHER, int EPI,
          int MINW>
__global__ __launch_bounds__(256, MINW) void gemm_mfma(
    const int* __restrict__ ids,
    const float* __restrict__ A1, int lda1, int K1,
    const float* __restrict__ A2, int lda2, int K2,
    const float* __restrict__ W1, int ldw1,
    const float* __restrict__ W2, int ldw2,
    const float* __restrict__ bias1, const float* __restrict__ bias2,
    float* __restrict__ C, int ldc, int N,
    unsigned* ctr, const float* __restrict__ xc,
    float* __restrict__ xh, float* __restrict__ xo) {
  constexpr int LP = BK + 8;       // LDS row pitch in bf16 (+8 pad)
  constexpr int KQ = BK / 4;       // float4 chunks per row
  constexpr int KSUB = BK / 32;    // MFMA K-subtiles per iteration
  constexpr int WAVES_N = (BN >= 64) ? 2 : 1;
  constexpr int WAVES_M = 4 / WAVES_N;
  constexpr int WM = BM / WAVES_M;
  constexpr int FM = WM / 16;
  constexpr int FN = BN / (16 * WAVES_N);  // 32->2, 64->2, 128->4
  constexpr int WN = FN * 16;
  constexpr int ACH = (BM * BK) / (4 * 256);
  constexpr int WCH = (BN * BK) / (4 * 256);
  constexpr int WVN = WTR ? (BK * 8 / 256) : WCH;

  __shared__ unsigned short Al[BM * LP];
  __shared__ unsigned short Wl[BN * LP];

  const int tid = threadIdx.x;
  const int wid = tid >> 6, lane = tid & 63;
  const int nBlock = blockIdx.x * BN;
  const int mBlock = blockIdx.y * BM;
  const int z = blockIdx.z;
  int wm, wn;
  if (WAVES_N == 2) { wm = (wid >> 1) * WM; wn = (wid & 1) * WN; }
  else              { wm = wid * WM;        wn = 0; }

  float4 av[ACH], wv[WVN];

  auto load_tile = [&](int kg) {
    const bool seg1 = kg < K1;
    const float* Wseg = seg1 ? W1 : W2;
    const int ldw = seg1 ? ldw1 : ldw2;
    const int kloc = seg1 ? kg : kg - K1;
#pragma unroll
    for (int i = 0; i < ACH; i++) {
      int c = tid + i * 256;
      int m = c / KQ, kq = (c % KQ) * 4;
      const float* arow;
      if (seg1) {
        if (GATHER) arow = A1 + (size_t)ids[mBlock + m] * lda1;
        else        arow = A1 + (size_t)(mBlock + m) * lda1;
      } else {
        arow = A2 + (size_t)(mBlock + m) * lda2;
      }
      av[i] = *(const float4*)(arow + kloc + kq);
    }
    if (WTR) {
#pragma unroll
      for (int i = 0; i < WVN; i++) {
        int c = tid + i * 256;           // BK k-rows x 8 n-quads
        int row = c >> 3, colq = c & 7;
        wv[i] = *(const float4*)(Wseg + (size_t)(kloc + row) * ldw + nBlock + colq * 4);
      }
    } else {
#pragma unroll
      for (int i = 0; i < WCH; i++) {
        int c = tid + i * 256;
        int n = c / KQ, kq = (c % KQ) * 4;
        wv[i] = *(const float4*)(Wseg + (size_t)(nBlock + n) * ldw + kloc + kq);
      }
    }
  };

  const int KT = K1 + K2;
  const int KS = KT / SPLIT;          // per-split K (multiple of BK; segment-aligned)
  const int kbeg = z * KS;
  const int NS = KS / BK;
  load_tile(kbeg);
  f32x4 acc[FM][FN] = {};

  for (int step = 0; step < NS; ++step) {
    __syncthreads();  // previous iteration's fragment reads done
    // commit regs -> LDS (f32 -> bf16, packed 8B stores)
#pragma unroll
    for (int i = 0; i < ACH; i++) {
      int c = tid + i * 256;
      int m = c / KQ, kq = (c % KQ) * 4;
      *(uint2*)&Al[m * LP + kq] = cvt4(av[i]);
    }
    if (WTR) {
#pragma unroll
      for (int i = 0; i < WVN; i++) {
        int c = tid + i * 256;
        int row = c >> 3, colq = c & 7;
        Wl[(colq * 4 + 0) * LP + row] = cvt1(wv[i].x);
        Wl[(colq * 4 + 1) * LP + row] = cvt1(wv[i].y);
        Wl[(colq * 4 + 2) * LP + row] = cvt1(wv[i].z);
        Wl[(colq * 4 + 3) * LP + row] = cvt1(wv[i].w);
      }
    } else {
#pragma unroll
      for (int i = 0; i < WCH; i++) {
        int c = tid + i * 256;
        int n = c / KQ, kq = (c % KQ) * 4;
        *(uint2*)&Wl[n * LP + kq] = cvt4(wv[i]);
      }
    }
    __syncthreads();

    if (step + 1 < NS) load_tile(kbeg + (step + 1) * BK);  // prefetch

    const int klane = (lane >> 4) << 3;
    const int r = lane & 15;
    short8 af[KSUB][FM], wf[KSUB][FN];
#pragma unroll
    for (int ks = 0; ks < KSUB; ks++) {
#pragma unroll
      for (int f = 0; f < FM; f++)
        af[ks][f] = *(const short8*)&Al[(wm + f * 16 + r) * LP + ks * 32 + klane];
#pragma unroll
      for (int f = 0; f < FN; f++)
        wf[ks][f] = *(const short8*)&Wl[(wn + f * 16 + r) * LP + ks * 32 + klane];
    }
#pragma unroll
    for (int ks = 0; ks < KSUB; ks++)
#pragma unroll
      for (int fm = 0; fm < FM; fm++)
#pragma unroll
        for (int fn = 0; fn < FN; fn++)
          acc[fm][fn] = __builtin_amdgcn_mfma_f32_16x16x32_bf16(
              af[ks][fm], wf[ks][fn], acc[fm][fn], 0, 0, 0);
  }

  // Partial store. D layout: col = lane&15, row = (lane>>4)*4 + j
  float* Cp = C + (size_t)z * gridDim.y * BM * ldc;
  const int col = lane & 15, rb = (lane >> 4) << 2;
#pragma unroll
  for (int fn = 0; fn < FN; fn++) {
    int n = nBlock + wn + fn * 16 + col;
    float bsum = 0.f;
    if (z == 0) {
      if (bias1) bsum += bias1[n];
      if (bias2) bsum += bias2[n];
    }
#pragma unroll
    for (int fm = 0; fm < FM; fm++) {
#pragma unroll
      for (int j = 0; j < 4; j++) {
        int m = mBlock + wm + fm * 16 + rb + j;
        Cp[(size_t)m * ldc + n] = acc[fm][fn][j] + bsum;
      }
    }
  }

  if (EPI == 0) return;

  // ---- fused tail-block epilogue (last arriver per tile group) ----
  __syncthreads();          // all partial stores of this block issued
  __threadfence();          // make them agent-visible (release)
  __shared__ unsigned oldv;
  if (tid == 0) {
    int cidx;
    if (EPI == 1) cidx = (blockIdx.x & 31) + 32 * blockIdx.y;
    else          cidx = blockIdx.x + 32 * blockIdx.y;
    oldv = __hip_atomic_fetch_add(&ctr[cidx], 1u, __ATOMIC_ACQ_REL,
                                  __HIP_MEMORY_SCOPE_AGENT);
  }
  __syncthreads();
  const unsigned TOT = (EPI == 1) ? 4u * SPLIT : (unsigned)SPLIT;
  if (oldv != TOT - 1) return;

  if (EPI == 1) {
    // LSTM pointwise for tile (m: mBlock..+63, j: (x&31)*32..+31)
    const int j0 = (blockIdx.x & 31) * 32;
#pragma unroll
    for (int sl = 0; sl < 2; sl++) {
      int slot = tid + sl * 256;            // 512 slots = 64 m x 8 j-quads
      int m = mBlock + (slot >> 3), j = j0 + (slot & 7) * 4;
      float4 gs[4] = {};
      for (int zz = 0; zz < SPLIT; zz++) {
        const float* gp = C + (size_t)zz * gridDim.y * BM * ldc + (size_t)m * ldc;
#pragma unroll
        for (int g = 0; g < 4; g++) {
          float4 v = *(const float4*)(gp + g * 1024 + j);
          gs[g].x += v.x; gs[g].y += v.y; gs[g].z += v.z; gs[g].w += v.w;
        }
      }
      float4 c4 = *(const float4*)(xc + (size_t)m * 1024 + j);
      float4 h4, cn4;
      const float* gi = &gs[0].x; const float* gf = &gs[1].x;
      const float* gg = &gs[2].x; const float* go = &gs[3].x;
      float* cp = &c4.x; float* hp = &h4.x; float* cnp = &cn4.x;
#pragma unroll
      for (int u = 0; u < 4; u++) {
        float cn = sigm(gf[u]) * cp[u] + sigm(gi[u]) * tanhf(gg[u]);
        hp[u] = sigm(go[u]) * tanhf(cn);
        cnp[u] = cn;
      }
      *(float4*)(xh + (size_t)m * 1024 + j) = h4;
      *(float4*)(xo + (size_t)m * 1024 + j) = cn4;
    }
  } else {
    // concat tanh for tile (m: mBlock..+63, n: x*32..+31); pairwise sum
    const int n0 = blockIdx.x * 32;
#pragma unroll
    for (int sl = 0; sl < 2; sl++) {
      int slot = tid + sl * 256;
      int m = mBlock + (slot >> 3), j = n0 + (slot & 7) * 4;
      const size_t st = (size_t)gridDim.y * BM * ldc;
      const float* base = C + (size_t)m * ldc + j;
      float4 p0 = *(const float4*)(base);
      float4 p1 = *(const float4*)(base + st);
      float4 p2 = *(const float4*)(base + 2 * st);
      float4 p3 = *(const float4*)(base + 3 * st);
      float4 r;
      r.x = tanhf((p0.x + p1.x) + (p2.x + p3.x));
      r.y = tanhf((p0.y + p1.y) + (p2.y + p3.y));
      r.z = tanhf((p0.z + p1.z) + (p2.z + p3.z));
      r.w = tanhf((p0.w + p1.w) + (p2.w + p3.w));
      *(float4*)(xh + (size_t)m * 1024 + j) = r;
    }
  }
}

// ---------------------------------------------------------------------------
__global__ void zero_ctr(unsigned* c) {
  if (threadIdx.x < 192) c[threadIdx.x] = 0;
}

// ---------------------------------------------------------------------------
// scores[b,s] = <enc[s,b,:], q[b,:]>, q = sum of 4 split-K partials staged in
// LDS once per block (4 waves share b). attn_b term cancels in softmax.
__global__ void scores_k(const float* __restrict__ enc,
                         const float* __restrict__ qp,
                         float* __restrict__ sc) {
  int blk = blockIdx.x;           // B * S/4 = 8192
  int b = blk >> 6, s4 = blk & 63;
  int t = threadIdx.x;
  __shared__ float qs[1024];
  {
    const float4* q0 = (const float4*)(qp + (size_t)b * Hv);
    const float4* q1 = (const float4*)(qp + 1 * Bv * Hv + (size_t)b * Hv);
    const float4* q2 = (const float4*)(qp + 2 * Bv * Hv + (size_t)b * Hv);
    const float4* q3 = (const float4*)(qp + 3 * Bv * Hv + (size_t)b * Hv);
    float4 a = q0[t], bq = q1[t], c = q2[t], d = q3[t];
    float4 s;
    s.x = a.x + bq.x + c.x + d.x; s.y = a.y + bq.y + c.y + d.y;
    s.z = a.z + bq.z + c.z + d.z; s.w = a.w + bq.w + c.w + d.w;
    ((float4*)qs)[t] = s;
  }
  __syncthreads();
  int wid = t >> 6, lane = t & 63;
  int s = s4 * 4 + wid;
  const float4* e4 = (const float4*)(enc + ((size_t)s * Bv + b) * Hv);
  const float4* q4 = (const float4*)qs;
  float sum = 0.f;
#pragma unroll
  for (int i = 0; i < 4; i++) {
    int idx = lane + i * 64;
    float4 e = e4[idx], qq = q4[idx];
    sum += e.x * qq.x + e.y * qq.y + e.z * qq.z + e.w * qq.w;
  }
#pragma unroll
  for (int o = 32; o; o >>= 1) sum += __shfl_xor(sum, o);
  if (lane == 0) sc[(size_t)b * Sv + s] = sum;
}

// ---------------------------------------------------------------------------
// Per block (b, h-quarter): softmax over sc[b,:] (recomputed redundantly,
// cheap) then ctx[b, hc:hc+256] = sum_s attn[s] * enc[s,b,hc:hc+256].
__global__ void context_k(const float* __restrict__ sc_in,
                          const float* __restrict__ enc,
                          float* __restrict__ ctx) {
  int blk = blockIdx.x;                 // B * 4 = 512
  int b = blk >> 2, hc = (blk & 3) * 256;
  int t = threadIdx.x, lane = t & 63;
  __shared__ float a[256];
  __shared__ float redm[4], reds[4];
  float v = sc_in[(size_t)b * Sv + t];
  float m = v;
#pragma unroll
  for (int o = 32; o; o >>= 1) m = fmaxf(m, __shfl_xor(m, o));
  if (lane == 0) redm[t >> 6] = m;
  __syncthreads();
  m = fmaxf(fmaxf(redm[0], redm[1]), fmaxf(redm[2], redm[3]));
  float e = expf(v - m);
  float ssum = e;
#pragma unroll
  for (int o = 32; o; o >>= 1) ssum += __shfl_xor(ssum, o);
  if (lane == 0) reds[t >> 6] = ssum;
  __syncthreads();
  ssum = (reds[0] + reds[1]) + (reds[2] + reds[3]);
  a[t] = e / ssum;
  __syncthreads();

  float acc = 0.f;
  const float* ebase = enc + (size_t)b * Hv + hc + t;
#pragma unroll 8
  for (int s = 0; s < Sv; s++)
    acc += a[s] * ebase[(size_t)s * Bv * Hv];
  ctx[(size_t)b * Hv + hc + t] = acc;
}

// ---------------------------------------------------------------------------
extern "C" void kernel_launch(void* const* d_in, const int* in_sizes, int n_in,
                              void* d_out, int out_size, void* d_ws,
                              size_t ws_size, hipStream_t stream) {
  const int*   ids      = (const int*)d_in[0];
  const float* h0       = (const float*)d_in[1];
  const float* c0       = (const float*)d_in[2];
  const float* enc      = (const float*)d_in[3];
  const float* emb      = (const float*)d_in[4];
  const float* w_ih0    = (const float*)d_in[5];
  const float* w_hh0    = (const float*)d_in[6];
  const float* b_ih0    = (const float*)d_in[7];
  const float* b_hh0    = (const float*)d_in[8];
  const float* w_ih1    = (const float*)d_in[9];
  const float* w_hh1    = (const float*)d_in[10];
  const float* b_ih1    = (const float*)d_in[11];
  const float* b_hh1    = (const float*)d_in[12];
  const float* attn_w   = (const float*)d_in[13];
  const float* attn_b   = (const float*)d_in[14];  // cancels in softmax
  const float* concat_w = (const float*)d_in[15];
  const float* concat_b = (const float*)d_in[16];
  const float* out_w    = (const float*)d_in[17];
  const float* out_b    = (const float*)d_in[18];
  (void)attn_b;

  float* logits = (float*)d_out;                  // [128, 32000]
  float* hout   = logits + (size_t)Bv * Vv;       // [2, 128, 1024]
  float* cout   = hout + 2 * Bv * Hv;             // [2, 128, 1024]

  float* ws   = (float*)d_ws;
  float* G0p  = ws;                       // 3 * 524288
  float* G1p  = G0p + 3 * 524288;         // 4 * 524288
  float* qp   = G1p + 4 * (size_t)524288; // 4 * 131072
  float* catp = qp + 4 * 131072;          // 4 * 131072
  float* cat  = catp + 4 * 131072;        // 131072
  float* ctx  = cat + 131072;             // 131072
  float* sc   = ctx + 131072;             // 32768
  unsigned* ctr = (unsigned*)(sc + 32768);// 192 counters

  const float* h_b = hout + Bv * Hv;  // layer-1 h (rnn_out)

  // 0. zero split-K tail counters (d_ws is poisoned before timing)
  zero_ctr<<<1, 256, 0, stream>>>(ctr);
  // 1. LSTM layer 0: gates (K=512 emb + 1024 h0, 3-way split-K) + fused pw
  gemm_mfma<64, 32, 64, 3, 0, 1, 1, 4><<<dim3(128, 2, 3), 256, 0, stream>>>(
      ids, emb, Ev, Ev, h0, Hv, Hv, w_ih0, Ev, w_hh0, Hv, b_ih0, b_hh0,
      G0p, 4 * Hv, 4 * Hv, ctr, c0, hout, cout);
  // 2. LSTM layer 1: gates (K=1024 h_l0 + 1024 h0[1], 4-way) + fused pw
  gemm_mfma<64, 32, 64, 4, 0, 0, 1, 4><<<dim3(128, 2, 4), 256, 0, stream>>>(
      nullptr, hout, Hv, Hv, h0 + Bv * Hv, Hv, Hv, w_ih1, Hv, w_hh1, Hv,
      b_ih1, b_hh1, G1p, 4 * Hv, 4 * Hv, ctr + 64, c0 + Bv * Hv,
      hout + Bv * Hv, cout + Bv * Hv);
  // 3. q = rnn @ attn_w (transposed in staging), 4-way split-K
  gemm_mfma<64, 32, 64, 4, 1, 0, 0, 4><<<dim3(32, 2, 4), 256, 0, stream>>>(
      nullptr, h_b, Hv, Hv, nullptr, 0, 0, attn_w, Hv,
      nullptr, 0, nullptr, nullptr, qp, Hv, Hv,
      nullptr, nullptr, nullptr, nullptr);
  // 4. scores (sums q partials via LDS once per block)
  scores_k<<<8192, 256, 0, stream>>>(enc, qp, sc);
  // 5. softmax (redundant per block) + context
  context_k<<<512, 256, 0, stream>>>(sc, enc, ctx);
  // 6. concat gates (K=1024 rnn + 1024 ctx, 4-way split-K) + fused tanh
  gemm_mfma<64, 32, 64, 4, 0, 0, 2, 4><<<dim3(32, 2, 4), 256, 0, stream>>>(
      nullptr, h_b, Hv, Hv, ctx, Hv, Hv, concat_w, 2 * Hv,
      concat_w + Hv, 2 * Hv, concat_b, nullptr, catp, Hv, Hv,
      ctr + 128, nullptr, cat, nullptr);
  // 7. logits: BM=128/BN=128/BK=64, grid (250,1) -> out_w read exactly once
  gemm_mfma<128, 128, 64, 1, 0, 0, 0, 1><<<dim3(250, 1, 1), 256, 0, stream>>>(
      nullptr, cat, Hv, Hv, nullptr, 0, 0, out_w, Hv, nullptr, 0,
      out_b, nullptr, logits, Vv, Vv,
      nullptr, nullptr, nullptr, nullptr);
}

// Round 11
// 164.319 us; speedup vs baseline: 2.4680x; 2.4680x over previous
//
#include <hip/hip_runtime.h>
#include <hip/hip_bf16.h>
#include <cstddef>
#include <cstdint>

// Problem dims
constexpr int Bv = 128;   // batch
constexpr int Sv = 256;   // src len
constexpr int Hv = 1024;  // hidden
constexpr int Ev = 512;   // embed
constexpr int Vv = 32000; // vocab

typedef __attribute__((ext_vector_type(4))) float f32x4;
typedef __attribute__((ext_vector_type(8))) short short8;

// f32x4 -> 4 packed bf16 (RNE), via v_cvt_pk_bf16_f32.
__device__ __forceinline__ uint2 cvt4(float4 v) {
  union { __hip_bfloat162 b; unsigned u; } lo, hi;
  lo.b = __float22bfloat162_rn(float2{v.x, v.y});
  hi.b = __float22bfloat162_rn(float2{v.z, v.w});
  uint2 r;
  r.x = lo.u;
  r.y = hi.u;
  return r;
}
__device__ __forceinline__ unsigned short cvt1(float x) {
  union { __hip_bfloat16 b; unsigned short u; } c;
  c.b = __float2bfloat16(x);
  return c.u;
}

// ---------------------------------------------------------------------------
// MFMA GEMM with split-K partials:
//   Cp[z][m,n] = sum_{k in split z} A[m,k]*W[n,k]  (+bias on z==0)
// A = A1 (k<K1, optionally gathered emb rows) then A2. W row-major [N,K]
// unless WTR (W1 is [K,N], transposed during LDS staging; needs BN==32).
// BK: K-tile per iteration. Bigger BK = more loads in flight per wave.
// Partial z written at C + z*gridDim.y*BM*ldc. Consumers sum partials.
// NOTE (R10 lesson): no cross-block atomics/fences here — per-block
// agent-scope ACQ_REL on 8-XCD forces L2 writeback storms (17x slowdown).
// ---------------------------------------------------------------------------
template <int BM, int BN, int BK, int SPLIT, int WTR, int GATHER, int MINW>
__global__ __launch_bounds__(256, MINW) void gemm_mfma(
    const int* __restrict__ ids,
    const float* __restrict__ A1, int lda1, int K1,
    const float* __restrict__ A2, int lda2, int K2,
    const float* __restrict__ W1, int ldw1,
    const float* __restrict__ W2, int ldw2,
    const float* __restrict__ bias1, const float* __restrict__ bias2,
    float* __restrict__ C, int ldc, int N) {
  constexpr int LP = BK + 8;       // LDS row pitch in bf16 (+8 pad)
  constexpr int KQ = BK / 4;       // float4 chunks per row
  constexpr int KSUB = BK / 32;    // MFMA K-subtiles per iteration
  constexpr int WAVES_N = (BN >= 64) ? 2 : 1;
  constexpr int WAVES_M = 4 / WAVES_N;
  constexpr int WM = BM / WAVES_M;
  constexpr int FM = WM / 16;
  constexpr int FN = BN / (16 * WAVES_N);  // 32->2, 64->2, 128->4
  constexpr int WN = FN * 16;
  constexpr int ACH = (BM * BK) / (4 * 256);
  constexpr int WCH = (BN * BK) / (4 * 256);
  constexpr int WVN = WTR ? (BK * 8 / 256) : WCH;

  __shared__ unsigned short Al[BM * LP];
  __shared__ unsigned short Wl[BN * LP];

  const int tid = threadIdx.x;
  const int wid = tid >> 6, lane = tid & 63;
  const int nBlock = blockIdx.x * BN;
  const int mBlock = blockIdx.y * BM;
  const int z = blockIdx.z;
  int wm, wn;
  if (WAVES_N == 2) { wm = (wid >> 1) * WM; wn = (wid & 1) * WN; }
  else              { wm = wid * WM;        wn = 0; }

  float4 av[ACH], wv[WVN];

  auto load_tile = [&](int kg) {
    const bool seg1 = kg < K1;
    const float* Wseg = seg1 ? W1 : W2;
    const int ldw = seg1 ? ldw1 : ldw2;
    const int kloc = seg1 ? kg : kg - K1;
#pragma unroll
    for (int i = 0; i < ACH; i++) {
      int c = tid + i * 256;
      int m = c / KQ, kq = (c % KQ) * 4;
      const float* arow;
      if (seg1) {
        if (GATHER) arow = A1 + (size_t)ids[mBlock + m] * lda1;
        else        arow = A1 + (size_t)(mBlock + m) * lda1;
      } else {
        arow = A2 + (size_t)(mBlock + m) * lda2;
      }
      av[i] = *(const float4*)(arow + kloc + kq);
    }
    if (WTR) {
#pragma unroll
      for (int i = 0; i < WVN; i++) {
        int c = tid + i * 256;           // BK k-rows x 8 n-quads
        int row = c >> 3, colq = c & 7;
        wv[i] = *(const float4*)(Wseg + (size_t)(kloc + row) * ldw + nBlock + colq * 4);
      }
    } else {
#pragma unroll
      for (int i = 0; i < WCH; i++) {
        int c = tid + i * 256;
        int n = c / KQ, kq = (c % KQ) * 4;
        wv[i] = *(const float4*)(Wseg + (size_t)(nBlock + n) * ldw + kloc + kq);
      }
    }
  };

  const int KT = K1 + K2;
  const int KS = KT / SPLIT;          // per-split K (multiple of BK; segment-aligned)
  const int kbeg = z * KS;
  const int NS = KS / BK;
  load_tile(kbeg);
  f32x4 acc[FM][FN] = {};

  for (int step = 0; step < NS; ++step) {
    __syncthreads();  // previous iteration's fragment reads done
    // commit regs -> LDS (f32 -> bf16, packed 8B stores)
#pragma unroll
    for (int i = 0; i < ACH; i++) {
      int c = tid + i * 256;
      int m = c / KQ, kq = (c % KQ) * 4;
      *(uint2*)&Al[m * LP + kq] = cvt4(av[i]);
    }
    if (WTR) {
#pragma unroll
      for (int i = 0; i < WVN; i++) {
        int c = tid + i * 256;
        int row = c >> 3, colq = c & 7;
        Wl[(colq * 4 + 0) * LP + row] = cvt1(wv[i].x);
        Wl[(colq * 4 + 1) * LP + row] = cvt1(wv[i].y);
        Wl[(colq * 4 + 2) * LP + row] = cvt1(wv[i].z);
        Wl[(colq * 4 + 3) * LP + row] = cvt1(wv[i].w);
      }
    } else {
#pragma unroll
      for (int i = 0; i < WCH; i++) {
        int c = tid + i * 256;
        int n = c / KQ, kq = (c % KQ) * 4;
        *(uint2*)&Wl[n * LP + kq] = cvt4(wv[i]);
      }
    }
    __syncthreads();

    if (step + 1 < NS) load_tile(kbeg + (step + 1) * BK);  // prefetch

    const int klane = (lane >> 4) << 3;
    const int r = lane & 15;
    short8 af[KSUB][FM], wf[KSUB][FN];
#pragma unroll
    for (int ks = 0; ks < KSUB; ks++) {
#pragma unroll
      for (int f = 0; f < FM; f++)
        af[ks][f] = *(const short8*)&Al[(wm + f * 16 + r) * LP + ks * 32 + klane];
#pragma unroll
      for (int f = 0; f < FN; f++)
        wf[ks][f] = *(const short8*)&Wl[(wn + f * 16 + r) * LP + ks * 32 + klane];
    }
#pragma unroll
    for (int ks = 0; ks < KSUB; ks++)
#pragma unroll
      for (int fm = 0; fm < FM; fm++)
#pragma unroll
        for (int fn = 0; fn < FN; fn++)
          acc[fm][fn] = __builtin_amdgcn_mfma_f32_16x16x32_bf16(
              af[ks][fm], wf[ks][fn], acc[fm][fn], 0, 0, 0);
  }

  // Epilogue. D layout: col = lane&15, row = (lane>>4)*4 + j
  float* Cp = C + (size_t)z * gridDim.y * BM * ldc;
  const int col = lane & 15, rb = (lane >> 4) << 2;
#pragma unroll
  for (int fn = 0; fn < FN; fn++) {
    int n = nBlock + wn + fn * 16 + col;
    float bsum = 0.f;
    if (z == 0) {
      if (bias1) bsum += bias1[n];
      if (bias2) bsum += bias2[n];
    }
#pragma unroll
    for (int fm = 0; fm < FM; fm++) {
#pragma unroll
      for (int j = 0; j < 4; j++) {
        int m = mBlock + wm + fm * 16 + rb + j;
        Cp[(size_t)m * ldc + n] = acc[fm][fn][j] + bsum;
      }
    }
  }
}

// ---------------------------------------------------------------------------
template <int P>
__global__ void lstm_pw(const float* __restrict__ Gp,
                        const float* __restrict__ c_prev,
                        float* __restrict__ h_out,
                        float* __restrict__ c_out) {
  int i4 = blockIdx.x * 256 + threadIdx.x;  // 32768 float4 slots (B*H/4)
  int b = i4 >> 8, j4 = i4 & 255;
  float4 gi{}, gf{}, gg{}, go{};
#pragma unroll
  for (int p = 0; p < P; p++) {
    const float4* g = (const float4*)(Gp + (size_t)p * Bv * 4 * Hv + (size_t)b * 4096);
    float4 a = g[j4], bb = g[256 + j4], c = g[512 + j4], d = g[768 + j4];
    gi.x += a.x; gi.y += a.y; gi.z += a.z; gi.w += a.w;
    gf.x += bb.x; gf.y += bb.y; gf.z += bb.z; gf.w += bb.w;
    gg.x += c.x; gg.y += c.y; gg.z += c.z; gg.w += c.w;
    go.x += d.x; go.y += d.y; go.z += d.z; go.w += d.w;
  }
  float4 c4 = ((const float4*)c_prev)[i4];
  float4 h4, cn4;
  float* gip = &gi.x; float* gfp = &gf.x; float* ggp = &gg.x; float* gop = &go.x;
  float* cp = &c4.x; float* hp = &h4.x; float* cnp = &cn4.x;
#pragma unroll
  for (int u = 0; u < 4; u++) {
    float si = 1.f / (1.f + expf(-gip[u]));
    float sf = 1.f / (1.f + expf(-gfp[u]));
    float so = 1.f / (1.f + expf(-gop[u]));
    float cn = sf * cp[u] + si * tanhf(ggp[u]);
    hp[u] = so * tanhf(cn);
    cnp[u] = cn;
  }
  ((float4*)h_out)[i4] = h4;
  ((float4*)c_out)[i4] = cn4;
}

// ---------------------------------------------------------------------------
// scores[b,s] = <enc[s,b,:], q[b,:]> (q final, no partials). q staged in LDS
// once per block (4 waves share b). attn_b term cancels in softmax.
__global__ void scores_k(const float* __restrict__ enc,
                         const float* __restrict__ q,
                         float* __restrict__ sc) {
  int blk = blockIdx.x;           // B * S/4 = 8192
  int b = blk >> 6, s4 = blk & 63;
  int t = threadIdx.x;
  __shared__ float qs[1024];
  ((float4*)qs)[t] = ((const float4*)(q + (size_t)b * Hv))[t];
  __syncthreads();
  int wid = t >> 6, lane = t & 63;
  int s = s4 * 4 + wid;
  const float4* e4 = (const float4*)(enc + ((size_t)s * Bv + b) * Hv);
  const float4* q4 = (const float4*)qs;
  float sum = 0.f;
#pragma unroll
  for (int i = 0; i < 4; i++) {
    int idx = lane + i * 64;
    float4 e = e4[idx], qq = q4[idx];
    sum += e.x * qq.x + e.y * qq.y + e.z * qq.z + e.w * qq.w;
  }
#pragma unroll
  for (int o = 32; o; o >>= 1) sum += __shfl_xor(sum, o);
  if (lane == 0) sc[(size_t)b * Sv + s] = sum;
}

// ---------------------------------------------------------------------------
// Per block (b, h-quarter): softmax over sc[b,:] (recomputed redundantly,
// cheap), then ctx[b, hc:hc+256] = sum_s attn[s]*enc[s,b,hc:hc+256].
// Lane owns a float4 of h; the 4 waves split the s-range; LDS reduce.
__global__ void context_k(const float* __restrict__ sc_in,
                          const float* __restrict__ enc,
                          float* __restrict__ ctx) {
  int blk = blockIdx.x;                 // B * 4 = 512
  int b = blk >> 2, hc = (blk & 3) * 256;
  int t = threadIdx.x, lane = t & 63, wid = t >> 6;
  __shared__ float a[256];
  __shared__ float redm[4], reds[4];
  float v = sc_in[(size_t)b * Sv + t];
  float m = v;
#pragma unroll
  for (int o = 32; o; o >>= 1) m = fmaxf(m, __shfl_xor(m, o));
  if (lane == 0) redm[t >> 6] = m;
  __syncthreads();
  m = fmaxf(fmaxf(redm[0], redm[1]), fmaxf(redm[2], redm[3]));
  float e = expf(v - m);
  float ssum = e;
#pragma unroll
  for (int o = 32; o; o >>= 1) ssum += __shfl_xor(ssum, o);
  if (lane == 0) reds[t >> 6] = ssum;
  __syncthreads();
  ssum = (reds[0] + reds[1]) + (reds[2] + reds[3]);
  a[t] = e / ssum;
  __syncthreads();

  // each wave accumulates its 64-s slice; lane covers h = hc+lane*4..+3
  float4 acc = make_float4(0.f, 0.f, 0.f, 0.f);
  const float* ebase = enc + (size_t)b * Hv + hc + lane * 4;
#pragma unroll 8
  for (int s = wid * 64; s < wid * 64 + 64; s++) {
    float4 e = *(const float4*)(ebase + (size_t)s * Bv * Hv);
    float w = a[s];
    acc.x += w * e.x; acc.y += w * e.y; acc.z += w * e.z; acc.w += w * e.w;
  }
  __shared__ float4 part[4][64];
  part[wid][lane] = acc;
  __syncthreads();
  if (wid == 0) {
    float4 p0 = part[0][lane], p1 = part[1][lane];
    float4 p2 = part[2][lane], p3 = part[3][lane];
    float4 r;
    r.x = (p0.x + p1.x) + (p2.x + p3.x);
    r.y = (p0.y + p1.y) + (p2.y + p3.y);
    r.z = (p0.z + p1.z) + (p2.z + p3.z);
    r.w = (p0.w + p1.w) + (p2.w + p3.w);
    *(float4*)(ctx + (size_t)b * Hv + hc + lane * 4) = r;
  }
}

// ---------------------------------------------------------------------------
__global__ void finish_cat(const float* __restrict__ catp,
                           float* __restrict__ cat) {
  int i4 = blockIdx.x * 256 + threadIdx.x;  // 32768 float4 slots
  constexpr int ST = Bv * Hv / 4;
  const float4* p = (const float4*)catp;
  float4 a = p[i4], b = p[ST + i4], c = p[2 * ST + i4], d = p[3 * ST + i4];
  float4 r;
  r.x = tanhf(a.x + b.x + c.x + d.x);
  r.y = tanhf(a.y + b.y + c.y + d.y);
  r.z = tanhf(a.z + b.z + c.z + d.z);
  r.w = tanhf(a.w + b.w + c.w + d.w);
  ((float4*)cat)[i4] = r;
}

// ---------------------------------------------------------------------------
extern "C" void kernel_launch(void* const* d_in, const int* in_sizes, int n_in,
                              void* d_out, int out_size, void* d_ws,
                              size_t ws_size, hipStream_t stream) {
  const int*   ids      = (const int*)d_in[0];
  const float* h0       = (const float*)d_in[1];
  const float* c0       = (const float*)d_in[2];
  const float* enc      = (const float*)d_in[3];
  const float* emb      = (const float*)d_in[4];
  const float* w_ih0    = (const float*)d_in[5];
  const float* w_hh0    = (const float*)d_in[6];
  const float* b_ih0    = (const float*)d_in[7];
  const float* b_hh0    = (const float*)d_in[8];
  const float* w_ih1    = (const float*)d_in[9];
  const float* w_hh1    = (const float*)d_in[10];
  const float* b_ih1    = (const float*)d_in[11];
  const float* b_hh1    = (const float*)d_in[12];
  const float* attn_w   = (const float*)d_in[13];
  const float* attn_b   = (const float*)d_in[14];  // cancels in softmax
  const float* concat_w = (const float*)d_in[15];
  const float* concat_b = (const float*)d_in[16];
  const float* out_w    = (const float*)d_in[17];
  const float* out_b    = (const float*)d_in[18];
  (void)attn_b;

  float* logits = (float*)d_out;                  // [128, 32000]
  float* hout   = logits + (size_t)Bv * Vv;       // [2, 128, 1024]
  float* cout   = hout + 2 * Bv * Hv;             // [2, 128, 1024]

  float* ws   = (float*)d_ws;
  float* G0p  = ws;                       // 3 * 524288
  float* G1p  = G0p + 3 * 524288;         // 4 * 524288
  float* q    = G1p + 4 * (size_t)524288; // 131072
  float* catp = q + 4 * 131072;           // 4 * 131072
  float* cat  = catp + 4 * 131072;        // 131072
  float* ctx  = cat + 131072;             // 131072
  float* sc   = ctx + 131072;             // 32768

  const float* h_b = hout + Bv * Hv;  // layer-1 h (rnn_out)

  // 1. LSTM layer 0 gates: K = 512(emb,gathered) + 1024(h0), 3-way split-K
  gemm_mfma<64, 32, 64, 3, 0, 1, 4><<<dim3(128, 2, 3), 256, 0, stream>>>(
      ids, emb, Ev, Ev, h0, Hv, Hv, w_ih0, Ev, w_hh0, Hv, b_ih0, b_hh0,
      G0p, 4 * Hv, 4 * Hv);
  // 2. LSTM layer 0 pointwise (sums 3 partials); h -> hout[0]
  lstm_pw<3><<<128, 256, 0, stream>>>(G0p, c0, hout, cout);
  // 3. LSTM layer 1 gates: K = 1024(h_layer0) + 1024(h0[1]), 4-way split-K
  gemm_mfma<64, 32, 64, 4, 0, 0, 4><<<dim3(128, 2, 4), 256, 0, stream>>>(
      nullptr, hout, Hv, Hv, h0 + Bv * Hv, Hv, Hv, w_ih1, Hv, w_hh1, Hv,
      b_ih1, b_hh1, G1p, 4 * Hv, 4 * Hv);
  // 4. LSTM layer 1 pointwise (sums 4 partials)
  lstm_pw<4><<<128, 256, 0, stream>>>(G1p, c0 + Bv * Hv, hout + Bv * Hv,
                                      cout + Bv * Hv);
  // 5. q = rnn @ attn_w (transposed in staging), single-K (q final)
  gemm_mfma<64, 32, 64, 1, 1, 0, 4><<<dim3(32, 2, 1), 256, 0, stream>>>(
      nullptr, h_b, Hv, Hv, nullptr, 0, 0, attn_w, Hv,
      nullptr, 0, nullptr, nullptr, q, Hv, Hv);
  // 6. scores (q staged once per block via LDS)
  scores_k<<<8192, 256, 0, stream>>>(enc, q, sc);
  // 7. softmax (redundant per block) + context, float4 lanes
  context_k<<<512, 256, 0, stream>>>(sc, enc, ctx);
  // 8. concat gates: K = 1024(rnn) + 1024(ctx), 4-way split-K
  gemm_mfma<64, 32, 64, 4, 0, 0, 4><<<dim3(32, 2, 4), 256, 0, stream>>>(
      nullptr, h_b, Hv, Hv, ctx, Hv, Hv, concat_w, 2 * Hv,
      concat_w + Hv, 2 * Hv, concat_b, nullptr, catp, Hv, Hv);
  // 9. cat = tanh(sum of partials)
  finish_cat<<<128, 256, 0, stream>>>(catp, cat);
  // 10. logits: BM=128/BN=128/BK=64, grid (250,1) -> out_w read exactly once
  gemm_mfma<128, 128, 64, 1, 0, 0, 1><<<dim3(250, 1, 1), 256, 0, stream>>>(
      nullptr, cat, Hv, Hv, nullptr, 0, 0, out_w, Hv, nullptr, 0,
      out_b, nullptr, logits, Vv, Vv);
}

// Round 12
// 159.294 us; speedup vs baseline: 2.5458x; 1.0315x over previous
//
#include <hip/hip_runtime.h>
#include <hip/hip_bf16.h>
#include <cstddef>
#include <cstdint>

// Problem dims
constexpr int Bv = 128;   // batch
constexpr int Sv = 256;   // src len
constexpr int Hv = 1024;  // hidden
constexpr int Ev = 512;   // embed
constexpr int Vv = 32000; // vocab

typedef __attribute__((ext_vector_type(4))) float f32x4;
typedef __attribute__((ext_vector_type(8))) short short8;

// f32x4 -> 4 packed bf16 (RNE), via v_cvt_pk_bf16_f32.
__device__ __forceinline__ uint2 cvt4(float4 v) {
  union { __hip_bfloat162 b; unsigned u; } lo, hi;
  lo.b = __float22bfloat162_rn(float2{v.x, v.y});
  hi.b = __float22bfloat162_rn(float2{v.z, v.w});
  uint2 r;
  r.x = lo.u;
  r.y = hi.u;
  return r;
}
__device__ __forceinline__ unsigned short cvt1(float x) {
  union { __hip_bfloat16 b; unsigned short u; } c;
  c.b = __float2bfloat16(x);
  return c.u;
}

// ---------------------------------------------------------------------------
// MFMA GEMM with split-K partials:
//   Cp[z][m,n] = sum_{k in split z} A[m,k]*W[n,k]  (+bias on z==0)
// A = A1 (k<K1, optionally gathered emb rows) then A2. W row-major [N,K]
// unless WTR (W1 is [K,N], transposed during LDS staging; needs BN==32).
// BK: K-tile per iteration. Bigger BK = more loads in flight per wave.
// Partial z written at C + z*gridDim.y*BM*ldc. Consumers sum partials.
// NOTE (R10 lesson): no cross-block atomics/fences here — per-block
// agent-scope ACQ_REL on 8-XCD forces L2 writeback storms (17x slowdown).
// ---------------------------------------------------------------------------
template <int BM, int BN, int BK, int SPLIT, int WTR, int GATHER, int MINW>
__global__ __launch_bounds__(256, MINW) void gemm_mfma(
    const int* __restrict__ ids,
    const float* __restrict__ A1, int lda1, int K1,
    const float* __restrict__ A2, int lda2, int K2,
    const float* __restrict__ W1, int ldw1,
    const float* __restrict__ W2, int ldw2,
    const float* __restrict__ bias1, const float* __restrict__ bias2,
    float* __restrict__ C, int ldc, int N) {
  constexpr int LP = BK + 8;       // LDS row pitch in bf16 (+8 pad)
  constexpr int KQ = BK / 4;       // float4 chunks per row
  constexpr int KSUB = BK / 32;    // MFMA K-subtiles per iteration
  constexpr int WAVES_N = (BN >= 64) ? 2 : 1;
  constexpr int WAVES_M = 4 / WAVES_N;
  constexpr int WM = BM / WAVES_M;
  constexpr int FM = WM / 16;
  constexpr int FN = BN / (16 * WAVES_N);  // 32->2, 64->2, 128->4
  constexpr int WN = FN * 16;
  constexpr int ACH = (BM * BK) / (4 * 256);
  constexpr int WCH = (BN * BK) / (4 * 256);
  constexpr int WVN = WTR ? (BK * 8 / 256) : WCH;

  __shared__ unsigned short Al[BM * LP];
  __shared__ unsigned short Wl[BN * LP];

  const int tid = threadIdx.x;
  const int wid = tid >> 6, lane = tid & 63;
  const int nBlock = blockIdx.x * BN;
  const int mBlock = blockIdx.y * BM;
  const int z = blockIdx.z;
  int wm, wn;
  if (WAVES_N == 2) { wm = (wid >> 1) * WM; wn = (wid & 1) * WN; }
  else              { wm = wid * WM;        wn = 0; }

  float4 av[ACH], wv[WVN];

  auto load_tile = [&](int kg) {
    const bool seg1 = kg < K1;
    const float* Wseg = seg1 ? W1 : W2;
    const int ldw = seg1 ? ldw1 : ldw2;
    const int kloc = seg1 ? kg : kg - K1;
#pragma unroll
    for (int i = 0; i < ACH; i++) {
      int c = tid + i * 256;
      int m = c / KQ, kq = (c % KQ) * 4;
      const float* arow;
      if (seg1) {
        if (GATHER) arow = A1 + (size_t)ids[mBlock + m] * lda1;
        else        arow = A1 + (size_t)(mBlock + m) * lda1;
      } else {
        arow = A2 + (size_t)(mBlock + m) * lda2;
      }
      av[i] = *(const float4*)(arow + kloc + kq);
    }
    if (WTR) {
#pragma unroll
      for (int i = 0; i < WVN; i++) {
        int c = tid + i * 256;           // BK k-rows x 8 n-quads
        int row = c >> 3, colq = c & 7;
        wv[i] = *(const float4*)(Wseg + (size_t)(kloc + row) * ldw + nBlock + colq * 4);
      }
    } else {
#pragma unroll
      for (int i = 0; i < WCH; i++) {
        int c = tid + i * 256;
        int n = c / KQ, kq = (c % KQ) * 4;
        wv[i] = *(const float4*)(Wseg + (size_t)(nBlock + n) * ldw + kloc + kq);
      }
    }
  };

  const int KT = K1 + K2;
  const int KS = KT / SPLIT;          // per-split K (multiple of BK; segment-aligned)
  const int kbeg = z * KS;
  const int NS = KS / BK;
  load_tile(kbeg);
  f32x4 acc[FM][FN] = {};

  for (int step = 0; step < NS; ++step) {
    __syncthreads();  // previous iteration's fragment reads done
    // commit regs -> LDS (f32 -> bf16, packed 8B stores)
#pragma unroll
    for (int i = 0; i < ACH; i++) {
      int c = tid + i * 256;
      int m = c / KQ, kq = (c % KQ) * 4;
      *(uint2*)&Al[m * LP + kq] = cvt4(av[i]);
    }
    if (WTR) {
#pragma unroll
      for (int i = 0; i < WVN; i++) {
        int c = tid + i * 256;
        int row = c >> 3, colq = c & 7;
        Wl[(colq * 4 + 0) * LP + row] = cvt1(wv[i].x);
        Wl[(colq * 4 + 1) * LP + row] = cvt1(wv[i].y);
        Wl[(colq * 4 + 2) * LP + row] = cvt1(wv[i].z);
        Wl[(colq * 4 + 3) * LP + row] = cvt1(wv[i].w);
      }
    } else {
#pragma unroll
      for (int i = 0; i < WCH; i++) {
        int c = tid + i * 256;
        int n = c / KQ, kq = (c % KQ) * 4;
        *(uint2*)&Wl[n * LP + kq] = cvt4(wv[i]);
      }
    }
    __syncthreads();

    if (step + 1 < NS) load_tile(kbeg + (step + 1) * BK);  // prefetch

    const int klane = (lane >> 4) << 3;
    const int r = lane & 15;
    short8 af[KSUB][FM], wf[KSUB][FN];
#pragma unroll
    for (int ks = 0; ks < KSUB; ks++) {
#pragma unroll
      for (int f = 0; f < FM; f++)
        af[ks][f] = *(const short8*)&Al[(wm + f * 16 + r) * LP + ks * 32 + klane];
#pragma unroll
      for (int f = 0; f < FN; f++)
        wf[ks][f] = *(const short8*)&Wl[(wn + f * 16 + r) * LP + ks * 32 + klane];
    }
#pragma unroll
    for (int ks = 0; ks < KSUB; ks++)
#pragma unroll
      for (int fm = 0; fm < FM; fm++)
#pragma unroll
        for (int fn = 0; fn < FN; fn++)
          acc[fm][fn] = __builtin_amdgcn_mfma_f32_16x16x32_bf16(
              af[ks][fm], wf[ks][fn], acc[fm][fn], 0, 0, 0);
  }

  // Epilogue. D layout: col = lane&15, row = (lane>>4)*4 + j
  float* Cp = C + (size_t)z * gridDim.y * BM * ldc;
  const int col = lane & 15, rb = (lane >> 4) << 2;
#pragma unroll
  for (int fn = 0; fn < FN; fn++) {
    int n = nBlock + wn + fn * 16 + col;
    float bsum = 0.f;
    if (z == 0) {
      if (bias1) bsum += bias1[n];
      if (bias2) bsum += bias2[n];
    }
#pragma unroll
    for (int fm = 0; fm < FM; fm++) {
#pragma unroll
      for (int j = 0; j < 4; j++) {
        int m = mBlock + wm + fm * 16 + rb + j;
        Cp[(size_t)m * ldc + n] = acc[fm][fn][j] + bsum;
      }
    }
  }
}

// ---------------------------------------------------------------------------
template <int P>
__global__ void lstm_pw(const float* __restrict__ Gp,
                        const float* __restrict__ c_prev,
                        float* __restrict__ h_out,
                        float* __restrict__ c_out) {
  int i4 = blockIdx.x * 256 + threadIdx.x;  // 32768 float4 slots (B*H/4)
  int b = i4 >> 8, j4 = i4 & 255;
  float4 gi{}, gf{}, gg{}, go{};
#pragma unroll
  for (int p = 0; p < P; p++) {
    const float4* g = (const float4*)(Gp + (size_t)p * Bv * 4 * Hv + (size_t)b * 4096);
    float4 a = g[j4], bb = g[256 + j4], c = g[512 + j4], d = g[768 + j4];
    gi.x += a.x; gi.y += a.y; gi.z += a.z; gi.w += a.w;
    gf.x += bb.x; gf.y += bb.y; gf.z += bb.z; gf.w += bb.w;
    gg.x += c.x; gg.y += c.y; gg.z += c.z; gg.w += c.w;
    go.x += d.x; go.y += d.y; go.z += d.z; go.w += d.w;
  }
  float4 c4 = ((const float4*)c_prev)[i4];
  float4 h4, cn4;
  float* gip = &gi.x; float* gfp = &gf.x; float* ggp = &gg.x; float* gop = &go.x;
  float* cp = &c4.x; float* hp = &h4.x; float* cnp = &cn4.x;
#pragma unroll
  for (int u = 0; u < 4; u++) {
    float si = 1.f / (1.f + expf(-gip[u]));
    float sf = 1.f / (1.f + expf(-gfp[u]));
    float so = 1.f / (1.f + expf(-gop[u]));
    float cn = sf * cp[u] + si * tanhf(ggp[u]);
    hp[u] = so * tanhf(cn);
    cnp[u] = cn;
  }
  ((float4*)h_out)[i4] = h4;
  ((float4*)c_out)[i4] = cn4;
}

// ---------------------------------------------------------------------------
// Chunked flash-style attention, pass 1. Grid (128 b, 4 chunks), 256 thr.
// Per block: q[b] (sum of 4 split-K partials) -> LDS; scores for its 64 s
// (each wave 16 wave-dots); local max m_c + denom d_c; partial numerator
// num[c,b,h] = sum_s e^{sc_s - m_c} enc[s,b,h] with all 4 waves walking the
// SAME s-row per iteration (fast access shape, rows hot in L2/L3 from the
// score pass). enc is read from HBM exactly once across the whole grid.
__global__ __launch_bounds__(256) void attn_part(
    const float* __restrict__ enc, const float* __restrict__ qp,
    float* __restrict__ numb, float2* __restrict__ mden) {
  const int b = blockIdx.x, ch = blockIdx.y;
  const int t = threadIdx.x, lane = t & 63, wid = t >> 6;
  const int sbase = ch * 64;
  __shared__ float qs[1024];
  __shared__ float es[64];
  {
    const float4* q0 = (const float4*)(qp + (size_t)b * Hv);
    const float4* q1 = (const float4*)(qp + 1 * Bv * Hv + (size_t)b * Hv);
    const float4* q2 = (const float4*)(qp + 2 * Bv * Hv + (size_t)b * Hv);
    const float4* q3 = (const float4*)(qp + 3 * Bv * Hv + (size_t)b * Hv);
    float4 a = q0[t], bq = q1[t], c = q2[t], d = q3[t];
    float4 s;
    s.x = a.x + bq.x + c.x + d.x; s.y = a.y + bq.y + c.y + d.y;
    s.z = a.z + bq.z + c.z + d.z; s.w = a.w + bq.w + c.w + d.w;
    ((float4*)qs)[t] = s;
  }
  __syncthreads();

  // scores: wave wid covers s = sbase + wid*16 .. +15
  const float4* q4 = (const float4*)qs;
  for (int i = 0; i < 16; i++) {
    int s = sbase + wid * 16 + i;
    const float4* e4 = (const float4*)(enc + ((size_t)s * Bv + b) * Hv);
    float sum = 0.f;
#pragma unroll
    for (int j = 0; j < 4; j++) {
      int idx = lane + j * 64;
      float4 e = e4[idx], qq = q4[idx];
      sum += e.x * qq.x + e.y * qq.y + e.z * qq.z + e.w * qq.w;
    }
#pragma unroll
    for (int o = 32; o; o >>= 1) sum += __shfl_xor(sum, o);
    if (lane == 0) es[wid * 16 + i] = sum;
  }
  __syncthreads();

  // local softmax pieces (wave 0 only; 64 scores = 64 lanes)
  if (wid == 0) {
    float v = es[lane];
    float m = v;
#pragma unroll
    for (int o = 32; o; o >>= 1) m = fmaxf(m, __shfl_xor(m, o));
    float e = expf(v - m);
    float den = e;
#pragma unroll
    for (int o = 32; o; o >>= 1) den += __shfl_xor(den, o);
    es[lane] = e;
    if (lane == 0) mden[b * 4 + ch] = make_float2(m, den);
  }
  __syncthreads();

  // partial numerator: thread t owns h = t*4..t*4+3; whole block walks the
  // same s-row together (4 KB coalesced per iteration).
  float4 acc = make_float4(0.f, 0.f, 0.f, 0.f);
  const float* ebase = enc + ((size_t)sbase * Bv + b) * Hv + t * 4;
#pragma unroll 4
  for (int s = 0; s < 64; s++) {
    float4 e = *(const float4*)(ebase + (size_t)s * Bv * Hv);
    float w = es[s];
    acc.x += w * e.x; acc.y += w * e.y; acc.z += w * e.z; acc.w += w * e.w;
  }
  *(float4*)(numb + ((size_t)ch * Bv + b) * Hv + t * 4) = acc;
}

// ---------------------------------------------------------------------------
// Pass 2: exact recombination over the 4 chunks.
__global__ __launch_bounds__(256) void attn_fin(
    const float* __restrict__ numb, const float2* __restrict__ mden,
    float* __restrict__ ctx) {
  const int b = blockIdx.x, t = threadIdx.x;
  float2 md0 = mden[b * 4 + 0], md1 = mden[b * 4 + 1];
  float2 md2 = mden[b * 4 + 2], md3 = mden[b * 4 + 3];
  float M = fmaxf(fmaxf(md0.x, md1.x), fmaxf(md2.x, md3.x));
  float s0 = expf(md0.x - M), s1 = expf(md1.x - M);
  float s2 = expf(md2.x - M), s3 = expf(md3.x - M);
  float inv = 1.f / (s0 * md0.y + s1 * md1.y + s2 * md2.y + s3 * md3.y);
  const float4* n0 = (const float4*)(numb + (size_t)b * Hv);
  const float4* n1 = (const float4*)(numb + 1 * (size_t)Bv * Hv + (size_t)b * Hv);
  const float4* n2 = (const float4*)(numb + 2 * (size_t)Bv * Hv + (size_t)b * Hv);
  const float4* n3 = (const float4*)(numb + 3 * (size_t)Bv * Hv + (size_t)b * Hv);
  float4 a = n0[t], bb = n1[t], c = n2[t], d = n3[t];
  float4 r;
  r.x = (s0 * a.x + s1 * bb.x + s2 * c.x + s3 * d.x) * inv;
  r.y = (s0 * a.y + s1 * bb.y + s2 * c.y + s3 * d.y) * inv;
  r.z = (s0 * a.z + s1 * bb.z + s2 * c.z + s3 * d.z) * inv;
  r.w = (s0 * a.w + s1 * bb.w + s2 * c.w + s3 * d.w) * inv;
  ((float4*)(ctx + (size_t)b * Hv))[t] = r;
}

// ---------------------------------------------------------------------------
__global__ void finish_cat(const float* __restrict__ catp,
                           float* __restrict__ cat) {
  int i4 = blockIdx.x * 256 + threadIdx.x;  // 32768 float4 slots
  constexpr int ST = Bv * Hv / 4;
  const float4* p = (const float4*)catp;
  float4 a = p[i4], b = p[ST + i4], c = p[2 * ST + i4], d = p[3 * ST + i4];
  float4 r;
  r.x = tanhf(a.x + b.x + c.x + d.x);
  r.y = tanhf(a.y + b.y + c.y + d.y);
  r.z = tanhf(a.z + b.z + c.z + d.z);
  r.w = tanhf(a.w + b.w + c.w + d.w);
  ((float4*)cat)[i4] = r;
}

// ---------------------------------------------------------------------------
extern "C" void kernel_launch(void* const* d_in, const int* in_sizes, int n_in,
                              void* d_out, int out_size, void* d_ws,
                              size_t ws_size, hipStream_t stream) {
  const int*   ids      = (const int*)d_in[0];
  const float* h0       = (const float*)d_in[1];
  const float* c0       = (const float*)d_in[2];
  const float* enc      = (const float*)d_in[3];
  const float* emb      = (const float*)d_in[4];
  const float* w_ih0    = (const float*)d_in[5];
  const float* w_hh0    = (const float*)d_in[6];
  const float* b_ih0    = (const float*)d_in[7];
  const float* b_hh0    = (const float*)d_in[8];
  const float* w_ih1    = (const float*)d_in[9];
  const float* w_hh1    = (const float*)d_in[10];
  const float* b_ih1    = (const float*)d_in[11];
  const float* b_hh1    = (const float*)d_in[12];
  const float* attn_w   = (const float*)d_in[13];
  const float* attn_b   = (const float*)d_in[14];  // cancels in softmax
  const float* concat_w = (const float*)d_in[15];
  const float* concat_b = (const float*)d_in[16];
  const float* out_w    = (const float*)d_in[17];
  const float* out_b    = (const float*)d_in[18];
  (void)attn_b;

  float* logits = (float*)d_out;                  // [128, 32000]
  float* hout   = logits + (size_t)Bv * Vv;       // [2, 128, 1024]
  float* cout   = hout + 2 * Bv * Hv;             // [2, 128, 1024]

  float* ws   = (float*)d_ws;
  float* G0p  = ws;                       // 3 * 524288 (dead after step 2)
  float* G1p  = G0p + 3 * 524288;         // 4 * 524288
  float* qp   = G1p + 4 * (size_t)524288; // 4 * 131072
  float* catp = qp + 4 * 131072;          // 4 * 131072
  float* cat  = catp + 4 * 131072;        // 131072
  float* ctx  = cat + 131072;             // 131072
  float* numb = G0p;                      // 524288 (reuses dead G0p)
  float2* mden = (float2*)(G0p + 524288); // 512 float2

  const float* h_b = hout + Bv * Hv;  // layer-1 h (rnn_out)

  // 1. LSTM layer 0 gates: K = 512(emb,gathered) + 1024(h0), 3-way split-K
  gemm_mfma<64, 32, 64, 3, 0, 1, 4><<<dim3(128, 2, 3), 256, 0, stream>>>(
      ids, emb, Ev, Ev, h0, Hv, Hv, w_ih0, Ev, w_hh0, Hv, b_ih0, b_hh0,
      G0p, 4 * Hv, 4 * Hv);
  // 2. LSTM layer 0 pointwise (sums 3 partials); h -> hout[0]
  lstm_pw<3><<<128, 256, 0, stream>>>(G0p, c0, hout, cout);
  // 3. LSTM layer 1 gates: K = 1024(h_layer0) + 1024(h0[1]), 4-way split-K
  gemm_mfma<64, 32, 64, 4, 0, 0, 4><<<dim3(128, 2, 4), 256, 0, stream>>>(
      nullptr, hout, Hv, Hv, h0 + Bv * Hv, Hv, Hv, w_ih1, Hv, w_hh1, Hv,
      b_ih1, b_hh1, G1p, 4 * Hv, 4 * Hv);
  // 4. LSTM layer 1 pointwise (sums 4 partials)
  lstm_pw<4><<<128, 256, 0, stream>>>(G1p, c0 + Bv * Hv, hout + Bv * Hv,
                                      cout + Bv * Hv);
  // 5. q = rnn @ attn_w (transposed in staging), 4-way split-K
  gemm_mfma<64, 32, 64, 4, 1, 0, 4><<<dim3(32, 2, 4), 256, 0, stream>>>(
      nullptr, h_b, Hv, Hv, nullptr, 0, 0, attn_w, Hv,
      nullptr, 0, nullptr, nullptr, qp, Hv, Hv);
  // 6. fused scores+softmax-partials+partial-context (enc read once)
  attn_part<<<dim3(128, 4), 256, 0, stream>>>(enc, qp, numb, mden);
  // 7. exact chunk recombination -> ctx
  attn_fin<<<128, 256, 0, stream>>>(numb, mden, ctx);
  // 8. concat gates: K = 1024(rnn) + 1024(ctx), 4-way split-K
  gemm_mfma<64, 32, 64, 4, 0, 0, 4><<<dim3(32, 2, 4), 256, 0, stream>>>(
      nullptr, h_b, Hv, Hv, ctx, Hv, Hv, concat_w, 2 * Hv,
      concat_w + Hv, 2 * Hv, concat_b, nullptr, catp, Hv, Hv);
  // 9. cat = tanh(sum of partials)
  finish_cat<<<128, 256, 0, stream>>>(catp, cat);
  // 10. logits: BM=128/BN=128/BK=64, grid (250,1) -> out_w read exactly once
  gemm_mfma<128, 128, 64, 1, 0, 0, 1><<<dim3(250, 1, 1), 256, 0, stream>>>(
      nullptr, cat, Hv, Hv, nullptr, 0, 0, out_w, Hv, nullptr, 0,
      out_b, nullptr, logits, Vv, Vv);
}

// Round 13
// 156.904 us; speedup vs baseline: 2.5846x; 1.0152x over previous
//
#include <hip/hip_runtime.h>
#include <hip/hip_bf16.h>
#include <cstddef>
#include <cstdint>

// Problem dims
constexpr int Bv = 128;   // batch
constexpr int Sv = 256;   // src len
constexpr int Hv = 1024;  // hidden
constexpr int Ev = 512;   // embed
constexpr int Vv = 32000; // vocab

typedef __attribute__((ext_vector_type(4))) float f32x4;
typedef __attribute__((ext_vector_type(8))) short short8;

// f32x4 -> 4 packed bf16 (RNE), via v_cvt_pk_bf16_f32.
__device__ __forceinline__ uint2 cvt4(float4 v) {
  union { __hip_bfloat162 b; unsigned u; } lo, hi;
  lo.b = __float22bfloat162_rn(float2{v.x, v.y});
  hi.b = __float22bfloat162_rn(float2{v.z, v.w});
  uint2 r;
  r.x = lo.u;
  r.y = hi.u;
  return r;
}
__device__ __forceinline__ unsigned short cvt1(float x) {
  union { __hip_bfloat16 b; unsigned short u; } c;
  c.b = __float2bfloat16(x);
  return c.u;
}

// ---------------------------------------------------------------------------
// MFMA GEMM with split-K partials:
//   Cp[z][m,n] = sum_{k in split z} A[m,k]*W[n,k]  (+bias on z==0)
// A = A1 (k<K1, optionally gathered emb rows) then A2. W row-major [N,K]
// unless WTR (W1 is [K,N], transposed during LDS staging; needs BN==32).
// BK: K-tile per iteration. Bigger BK = more loads in flight per wave.
// Partial z written at C + z*gridDim.y*BM*ldc. Consumers sum partials.
// NOTE (R10 lesson): no cross-block atomics/fences — agent-scope ACQ_REL
// per block on 8-XCD forces L2 writeback storms (17x slowdown).
// ---------------------------------------------------------------------------
template <int BM, int BN, int BK, int SPLIT, int WTR, int GATHER, int MINW>
__global__ __launch_bounds__(256, MINW) void gemm_mfma(
    const int* __restrict__ ids,
    const float* __restrict__ A1, int lda1, int K1,
    const float* __restrict__ A2, int lda2, int K2,
    const float* __restrict__ W1, int ldw1,
    const float* __restrict__ W2, int ldw2,
    const float* __restrict__ bias1, const float* __restrict__ bias2,
    float* __restrict__ C, int ldc, int N) {
  constexpr int LP = BK + 8;       // LDS row pitch in bf16 (+8 pad)
  constexpr int KQ = BK / 4;       // float4 chunks per row
  constexpr int KSUB = BK / 32;    // MFMA K-subtiles per iteration
  constexpr int WAVES_N = (BN >= 64) ? 2 : 1;
  constexpr int WAVES_M = 4 / WAVES_N;
  constexpr int WM = BM / WAVES_M;
  constexpr int FM = WM / 16;
  constexpr int FN = BN / (16 * WAVES_N);  // 32->2, 64->2, 128->4
  constexpr int WN = FN * 16;
  constexpr int ACH = (BM * BK) / (4 * 256);
  constexpr int WCH = (BN * BK) / (4 * 256);
  constexpr int WVN = WTR ? (BK * 8 / 256) : WCH;

  __shared__ unsigned short Al[BM * LP];
  __shared__ unsigned short Wl[BN * LP];

  const int tid = threadIdx.x;
  const int wid = tid >> 6, lane = tid & 63;
  const int nBlock = blockIdx.x * BN;
  const int mBlock = blockIdx.y * BM;
  const int z = blockIdx.z;
  int wm, wn;
  if (WAVES_N == 2) { wm = (wid >> 1) * WM; wn = (wid & 1) * WN; }
  else              { wm = wid * WM;        wn = 0; }

  float4 av[ACH], wv[WVN];

  auto load_tile = [&](int kg) {
    const bool seg1 = kg < K1;
    const float* Wseg = seg1 ? W1 : W2;
    const int ldw = seg1 ? ldw1 : ldw2;
    const int kloc = seg1 ? kg : kg - K1;
#pragma unroll
    for (int i = 0; i < ACH; i++) {
      int c = tid + i * 256;
      int m = c / KQ, kq = (c % KQ) * 4;
      const float* arow;
      if (seg1) {
        if (GATHER) arow = A1 + (size_t)ids[mBlock + m] * lda1;
        else        arow = A1 + (size_t)(mBlock + m) * lda1;
      } else {
        arow = A2 + (size_t)(mBlock + m) * lda2;
      }
      av[i] = *(const float4*)(arow + kloc + kq);
    }
    if (WTR) {
#pragma unroll
      for (int i = 0; i < WVN; i++) {
        int c = tid + i * 256;           // BK k-rows x 8 n-quads
        int row = c >> 3, colq = c & 7;
        wv[i] = *(const float4*)(Wseg + (size_t)(kloc + row) * ldw + nBlock + colq * 4);
      }
    } else {
#pragma unroll
      for (int i = 0; i < WCH; i++) {
        int c = tid + i * 256;
        int n = c / KQ, kq = (c % KQ) * 4;
        wv[i] = *(const float4*)(Wseg + (size_t)(nBlock + n) * ldw + kloc + kq);
      }
    }
  };

  const int KT = K1 + K2;
  const int KS = KT / SPLIT;          // per-split K (multiple of BK; segment-aligned)
  const int kbeg = z * KS;
  const int NS = KS / BK;
  load_tile(kbeg);
  f32x4 acc[FM][FN] = {};

  for (int step = 0; step < NS; ++step) {
    __syncthreads();  // previous iteration's fragment reads done
    // commit regs -> LDS (f32 -> bf16, packed 8B stores)
#pragma unroll
    for (int i = 0; i < ACH; i++) {
      int c = tid + i * 256;
      int m = c / KQ, kq = (c % KQ) * 4;
      *(uint2*)&Al[m * LP + kq] = cvt4(av[i]);
    }
    if (WTR) {
#pragma unroll
      for (int i = 0; i < WVN; i++) {
        int c = tid + i * 256;
        int row = c >> 3, colq = c & 7;
        Wl[(colq * 4 + 0) * LP + row] = cvt1(wv[i].x);
        Wl[(colq * 4 + 1) * LP + row] = cvt1(wv[i].y);
        Wl[(colq * 4 + 2) * LP + row] = cvt1(wv[i].z);
        Wl[(colq * 4 + 3) * LP + row] = cvt1(wv[i].w);
      }
    } else {
#pragma unroll
      for (int i = 0; i < WCH; i++) {
        int c = tid + i * 256;
        int n = c / KQ, kq = (c % KQ) * 4;
        *(uint2*)&Wl[n * LP + kq] = cvt4(wv[i]);
      }
    }
    __syncthreads();

    if (step + 1 < NS) load_tile(kbeg + (step + 1) * BK);  // prefetch

    const int klane = (lane >> 4) << 3;
    const int r = lane & 15;
    short8 af[KSUB][FM], wf[KSUB][FN];
#pragma unroll
    for (int ks = 0; ks < KSUB; ks++) {
#pragma unroll
      for (int f = 0; f < FM; f++)
        af[ks][f] = *(const short8*)&Al[(wm + f * 16 + r) * LP + ks * 32 + klane];
#pragma unroll
      for (int f = 0; f < FN; f++)
        wf[ks][f] = *(const short8*)&Wl[(wn + f * 16 + r) * LP + ks * 32 + klane];
    }
#pragma unroll
    for (int ks = 0; ks < KSUB; ks++)
#pragma unroll
      for (int fm = 0; fm < FM; fm++)
#pragma unroll
        for (int fn = 0; fn < FN; fn++)
          acc[fm][fn] = __builtin_amdgcn_mfma_f32_16x16x32_bf16(
              af[ks][fm], wf[ks][fn], acc[fm][fn], 0, 0, 0);
  }

  // Epilogue. D layout: col = lane&15, row = (lane>>4)*4 + j
  float* Cp = C + (size_t)z * gridDim.y * BM * ldc;
  const int col = lane & 15, rb = (lane >> 4) << 2;
#pragma unroll
  for (int fn = 0; fn < FN; fn++) {
    int n = nBlock + wn + fn * 16 + col;
    float bsum = 0.f;
    if (z == 0) {
      if (bias1) bsum += bias1[n];
      if (bias2) bsum += bias2[n];
    }
#pragma unroll
    for (int fm = 0; fm < FM; fm++) {
#pragma unroll
      for (int j = 0; j < 4; j++) {
        int m = mBlock + wm + fm * 16 + rb + j;
        Cp[(size_t)m * ldc + n] = acc[fm][fn][j] + bsum;
      }
    }
  }
}

// ---------------------------------------------------------------------------
template <int P>
__global__ void lstm_pw(const float* __restrict__ Gp,
                        const float* __restrict__ c_prev,
                        float* __restrict__ h_out,
                        float* __restrict__ c_out) {
  int i4 = blockIdx.x * 256 + threadIdx.x;  // 32768 float4 slots (B*H/4)
  int b = i4 >> 8, j4 = i4 & 255;
  float4 gi{}, gf{}, gg{}, go{};
#pragma unroll
  for (int p = 0; p < P; p++) {
    const float4* g = (const float4*)(Gp + (size_t)p * Bv * 4 * Hv + (size_t)b * 4096);
    float4 a = g[j4], bb = g[256 + j4], c = g[512 + j4], d = g[768 + j4];
    gi.x += a.x; gi.y += a.y; gi.z += a.z; gi.w += a.w;
    gf.x += bb.x; gf.y += bb.y; gf.z += bb.z; gf.w += bb.w;
    gg.x += c.x; gg.y += c.y; gg.z += c.z; gg.w += c.w;
    go.x += d.x; go.y += d.y; go.z += d.z; go.w += d.w;
  }
  float4 c4 = ((const float4*)c_prev)[i4];
  float4 h4, cn4;
  float* gip = &gi.x; float* gfp = &gf.x; float* ggp = &gg.x; float* gop = &go.x;
  float* cp = &c4.x; float* hp = &h4.x; float* cnp = &cn4.x;
#pragma unroll
  for (int u = 0; u < 4; u++) {
    float si = 1.f / (1.f + expf(-gip[u]));
    float sf = 1.f / (1.f + expf(-gfp[u]));
    float so = 1.f / (1.f + expf(-gop[u]));
    float cn = sf * cp[u] + si * tanhf(ggp[u]);
    hp[u] = so * tanhf(cn);
    cnp[u] = cn;
  }
  ((float4*)h_out)[i4] = h4;
  ((float4*)c_out)[i4] = cn4;
}

// ---------------------------------------------------------------------------
// scores[b,s] = <enc[s,b,:], q[b,:]>, q = sum of 4 split-K partials staged in
// LDS once per block (4 waves share b). attn_b term cancels in softmax.
__global__ void scores_k(const float* __restrict__ enc,
                         const float* __restrict__ qp,
                         float* __restrict__ sc) {
  int blk = blockIdx.x;           // B * S/4 = 8192
  int b = blk >> 6, s4 = blk & 63;
  int t = threadIdx.x;
  __shared__ float qs[1024];
  {
    const float4* q0 = (const float4*)(qp + (size_t)b * Hv);
    const float4* q1 = (const float4*)(qp + 1 * Bv * Hv + (size_t)b * Hv);
    const float4* q2 = (const float4*)(qp + 2 * Bv * Hv + (size_t)b * Hv);
    const float4* q3 = (const float4*)(qp + 3 * Bv * Hv + (size_t)b * Hv);
    float4 a = q0[t], bq = q1[t], c = q2[t], d = q3[t];
    float4 s;
    s.x = a.x + bq.x + c.x + d.x; s.y = a.y + bq.y + c.y + d.y;
    s.z = a.z + bq.z + c.z + d.z; s.w = a.w + bq.w + c.w + d.w;
    ((float4*)qs)[t] = s;
  }
  __syncthreads();
  int wid = t >> 6, lane = t & 63;
  int s = s4 * 4 + wid;
  const float4* e4 = (const float4*)(enc + ((size_t)s * Bv + b) * Hv);
  const float4* q4 = (const float4*)qs;
  float sum = 0.f;
#pragma unroll
  for (int i = 0; i < 4; i++) {
    int idx = lane + i * 64;
    float4 e = e4[idx], qq = q4[idx];
    sum += e.x * qq.x + e.y * qq.y + e.z * qq.z + e.w * qq.w;
  }
#pragma unroll
  for (int o = 32; o; o >>= 1) sum += __shfl_xor(sum, o);
  if (lane == 0) sc[(size_t)b * Sv + s] = sum;
}

// ---------------------------------------------------------------------------
// Context partial: block (b, hq, sq) recomputes the cheap softmax over
// sc[b,:], then accumulates 64 s-rows into ctxp[sq][b][hq*256..+255].
// Whole block walks the SAME s-row per iteration (proven access shape);
// 2048 blocks (8/CU) give the TLP the 512-block version lacked.
__global__ void context_part(const float* __restrict__ sc_in,
                             const float* __restrict__ enc,
                             float* __restrict__ ctxp) {
  int b = blockIdx.x, hq = blockIdx.y, sq = blockIdx.z;
  int t = threadIdx.x, lane = t & 63;
  __shared__ float a[256];
  __shared__ float redm[4], reds[4];
  float v = sc_in[(size_t)b * Sv + t];
  float m = v;
#pragma unroll
  for (int o = 32; o; o >>= 1) m = fmaxf(m, __shfl_xor(m, o));
  if (lane == 0) redm[t >> 6] = m;
  __syncthreads();
  m = fmaxf(fmaxf(redm[0], redm[1]), fmaxf(redm[2], redm[3]));
  float e = expf(v - m);
  float ssum = e;
#pragma unroll
  for (int o = 32; o; o >>= 1) ssum += __shfl_xor(ssum, o);
  if (lane == 0) reds[t >> 6] = ssum;
  __syncthreads();
  ssum = (reds[0] + reds[1]) + (reds[2] + reds[3]);
  a[t] = e / ssum;
  __syncthreads();

  float acc = 0.f;
  const float* ebase = enc + (size_t)b * Hv + hq * 256 + t;
#pragma unroll 8
  for (int s = sq * 64; s < sq * 64 + 64; s++)
    acc += a[s] * ebase[(size_t)s * Bv * Hv];
  ctxp[((size_t)sq * Bv + b) * Hv + hq * 256 + t] = acc;
}

// ---------------------------------------------------------------------------
__global__ void ctx_sum(const float* __restrict__ ctxp,
                        float* __restrict__ ctx) {
  int i4 = blockIdx.x * 256 + threadIdx.x;  // 32768 float4 slots
  constexpr int ST = Bv * Hv / 4;
  const float4* p = (const float4*)ctxp;
  float4 a = p[i4], b = p[ST + i4], c = p[2 * ST + i4], d = p[3 * ST + i4];
  float4 r;
  r.x = (a.x + b.x) + (c.x + d.x);
  r.y = (a.y + b.y) + (c.y + d.y);
  r.z = (a.z + b.z) + (c.z + d.z);
  r.w = (a.w + b.w) + (c.w + d.w);
  ((float4*)ctx)[i4] = r;
}

// ---------------------------------------------------------------------------
__global__ void finish_cat(const float* __restrict__ catp,
                           float* __restrict__ cat) {
  int i4 = blockIdx.x * 256 + threadIdx.x;  // 32768 float4 slots
  constexpr int ST = Bv * Hv / 4;
  const float4* p = (const float4*)catp;
  float4 a = p[i4], b = p[ST + i4], c = p[2 * ST + i4], d = p[3 * ST + i4];
  float4 r;
  r.x = tanhf(a.x + b.x + c.x + d.x);
  r.y = tanhf(a.y + b.y + c.y + d.y);
  r.z = tanhf(a.z + b.z + c.z + d.z);
  r.w = tanhf(a.w + b.w + c.w + d.w);
  ((float4*)cat)[i4] = r;
}

// ---------------------------------------------------------------------------
extern "C" void kernel_launch(void* const* d_in, const int* in_sizes, int n_in,
                              void* d_out, int out_size, void* d_ws,
                              size_t ws_size, hipStream_t stream) {
  const int*   ids      = (const int*)d_in[0];
  const float* h0       = (const float*)d_in[1];
  const float* c0       = (const float*)d_in[2];
  const float* enc      = (const float*)d_in[3];
  const float* emb      = (const float*)d_in[4];
  const float* w_ih0    = (const float*)d_in[5];
  const float* w_hh0    = (const float*)d_in[6];
  const float* b_ih0    = (const float*)d_in[7];
  const float* b_hh0    = (const float*)d_in[8];
  const float* w_ih1    = (const float*)d_in[9];
  const float* w_hh1    = (const float*)d_in[10];
  const float* b_ih1    = (const float*)d_in[11];
  const float* b_hh1    = (const float*)d_in[12];
  const float* attn_w   = (const float*)d_in[13];
  const float* attn_b   = (const float*)d_in[14];  // cancels in softmax
  const float* concat_w = (const float*)d_in[15];
  const float* concat_b = (const float*)d_in[16];
  const float* out_w    = (const float*)d_in[17];
  const float* out_b    = (const float*)d_in[18];
  (void)attn_b;

  float* logits = (float*)d_out;                  // [128, 32000]
  float* hout   = logits + (size_t)Bv * Vv;       // [2, 128, 1024]
  float* cout   = hout + 2 * Bv * Hv;             // [2, 128, 1024]

  float* ws   = (float*)d_ws;
  float* G0p  = ws;                       // 3 * 524288 (dead after step 2)
  float* G1p  = G0p + 3 * 524288;         // 4 * 524288
  float* qp   = G1p + 4 * (size_t)524288; // 4 * 131072
  float* catp = qp + 4 * 131072;          // 4 * 131072
  float* cat  = catp + 4 * 131072;        // 131072
  float* ctx  = cat + 131072;             // 131072
  float* sc   = ctx + 131072;             // 32768
  float* ctxp = G0p;                      // 4 * 131072 (reuses dead G0p)

  const float* h_b = hout + Bv * Hv;  // layer-1 h (rnn_out)

  // 1. LSTM layer 0 gates: K = 512(emb,gathered) + 1024(h0), 3-way split-K
  gemm_mfma<64, 32, 64, 3, 0, 1, 4><<<dim3(128, 2, 3), 256, 0, stream>>>(
      ids, emb, Ev, Ev, h0, Hv, Hv, w_ih0, Ev, w_hh0, Hv, b_ih0, b_hh0,
      G0p, 4 * Hv, 4 * Hv);
  // 2. LSTM layer 0 pointwise (sums 3 partials); h -> hout[0]
  lstm_pw<3><<<128, 256, 0, stream>>>(G0p, c0, hout, cout);
  // 3. LSTM layer 1 gates: K = 1024(h_layer0) + 1024(h0[1]), 4-way split-K
  gemm_mfma<64, 32, 64, 4, 0, 0, 4><<<dim3(128, 2, 4), 256, 0, stream>>>(
      nullptr, hout, Hv, Hv, h0 + Bv * Hv, Hv, Hv, w_ih1, Hv, w_hh1, Hv,
      b_ih1, b_hh1, G1p, 4 * Hv, 4 * Hv);
  // 4. LSTM layer 1 pointwise (sums 4 partials)
  lstm_pw<4><<<128, 256, 0, stream>>>(G1p, c0 + Bv * Hv, hout + Bv * Hv,
                                      cout + Bv * Hv);
  // 5. q = rnn @ attn_w (transposed in staging), 4-way split-K
  gemm_mfma<64, 32, 64, 4, 1, 0, 4><<<dim3(32, 2, 4), 256, 0, stream>>>(
      nullptr, h_b, Hv, Hv, nullptr, 0, 0, attn_w, Hv,
      nullptr, 0, nullptr, nullptr, qp, Hv, Hv);
  // 6. scores (8192 blocks; q partials summed via LDS once per block)
  scores_k<<<8192, 256, 0, stream>>>(enc, qp, sc);
  // 7. context partials: 2048 blocks (8/CU) -- s-range split 4-way
  context_part<<<dim3(128, 4, 4), 256, 0, stream>>>(sc, enc, ctxp);
  // 8. ctx = sum of 4 partials
  ctx_sum<<<128, 256, 0, stream>>>(ctxp, ctx);
  // 9. concat gates: K = 1024(rnn) + 1024(ctx), 4-way split-K
  gemm_mfma<64, 32, 64, 4, 0, 0, 4><<<dim3(32, 2, 4), 256, 0, stream>>>(
      nullptr, h_b, Hv, Hv, ctx, Hv, Hv, concat_w, 2 * Hv,
      concat_w + Hv, 2 * Hv, concat_b, nullptr, catp, Hv, Hv);
  // 10. cat = tanh(sum of partials)
  finish_cat<<<128, 256, 0, stream>>>(catp, cat);
  // 11. logits: BM=128/BN=128/BK=64, grid (250,1) -> out_w read exactly once
  gemm_mfma<128, 128, 64, 1, 0, 0, 1><<<dim3(250, 1, 1), 256, 0, stream>>>(
      nullptr, cat, Hv, Hv, nullptr, 0, 0, out_w, Hv, nullptr, 0,
      out_b, nullptr, logits, Vv, Vv);
}

// Round 14
// 150.846 us; speedup vs baseline: 2.6884x; 1.0402x over previous
//
#include <hip/hip_runtime.h>
#include <hip/hip_bf16.h>
#include <cstddef>
#include <cstdint>

// Problem dims
constexpr int Bv = 128;   // batch
constexpr int Sv = 256;   // src len
constexpr int Hv = 1024;  // hidden
constexpr int Ev = 512;   // embed
constexpr int Vv = 32000; // vocab

typedef __attribute__((ext_vector_type(4))) float f32x4;
typedef __attribute__((ext_vector_type(8))) short short8;

// f32x4 -> 4 packed bf16 (RNE), via v_cvt_pk_bf16_f32.
__device__ __forceinline__ uint2 cvt4(float4 v) {
  union { __hip_bfloat162 b; unsigned u; } lo, hi;
  lo.b = __float22bfloat162_rn(float2{v.x, v.y});
  hi.b = __float22bfloat162_rn(float2{v.z, v.w});
  uint2 r;
  r.x = lo.u;
  r.y = hi.u;
  return r;
}
__device__ __forceinline__ unsigned short cvt1(float x) {
  union { __hip_bfloat16 b; unsigned short u; } c;
  c.b = __float2bfloat16(x);
  return c.u;
}

// ---------------------------------------------------------------------------
// MFMA GEMM with split-K partials:
//   Cp[z][m,n] = sum_{k in split z} A[m,k]*W[n,k]  (+bias on z==0)
// A = A1 (k<K1, optionally gathered emb rows) then A2. W row-major [N,K]
// unless WTR (W1 is [K,N], transposed during LDS staging; needs BN==32).
// BK: K-tile per iteration. Bigger BK = more loads in flight per wave.
// Partial z written at C + z*gridDim.y*BM*ldc. Consumers sum partials.
// NOTE (R10 lesson): no cross-block atomics/fences — agent-scope ACQ_REL
// per block on 8-XCD forces L2 writeback storms (17x slowdown).
// ---------------------------------------------------------------------------
template <int BM, int BN, int BK, int SPLIT, int WTR, int GATHER, int MINW>
__global__ __launch_bounds__(256, MINW) void gemm_mfma(
    const int* __restrict__ ids,
    const float* __restrict__ A1, int lda1, int K1,
    const float* __restrict__ A2, int lda2, int K2,
    const float* __restrict__ W1, int ldw1,
    const float* __restrict__ W2, int ldw2,
    const float* __restrict__ bias1, const float* __restrict__ bias2,
    float* __restrict__ C, int ldc, int N) {
  constexpr int LP = BK + 8;       // LDS row pitch in bf16 (+8 pad)
  constexpr int KQ = BK / 4;       // float4 chunks per row
  constexpr int KSUB = BK / 32;    // MFMA K-subtiles per iteration
  constexpr int WAVES_N = (BN >= 64) ? 2 : 1;
  constexpr int WAVES_M = 4 / WAVES_N;
  constexpr int WM = BM / WAVES_M;
  constexpr int FM = WM / 16;
  constexpr int FN = BN / (16 * WAVES_N);  // 32->2, 64->2, 128->4
  constexpr int WN = FN * 16;
  constexpr int ACH = (BM * BK) / (4 * 256);
  constexpr int WCH = (BN * BK) / (4 * 256);
  constexpr int WVN = WTR ? (BK * 8 / 256) : WCH;

  __shared__ unsigned short Al[BM * LP];
  __shared__ unsigned short Wl[BN * LP];

  const int tid = threadIdx.x;
  const int wid = tid >> 6, lane = tid & 63;
  const int nBlock = blockIdx.x * BN;
  const int mBlock = blockIdx.y * BM;
  const int z = blockIdx.z;
  int wm, wn;
  if (WAVES_N == 2) { wm = (wid >> 1) * WM; wn = (wid & 1) * WN; }
  else              { wm = wid * WM;        wn = 0; }

  float4 av[ACH], wv[WVN];

  auto load_tile = [&](int kg) {
    const bool seg1 = kg < K1;
    const float* Wseg = seg1 ? W1 : W2;
    const int ldw = seg1 ? ldw1 : ldw2;
    const int kloc = seg1 ? kg : kg - K1;
#pragma unroll
    for (int i = 0; i < ACH; i++) {
      int c = tid + i * 256;
      int m = c / KQ, kq = (c % KQ) * 4;
      const float* arow;
      if (seg1) {
        if (GATHER) arow = A1 + (size_t)ids[mBlock + m] * lda1;
        else        arow = A1 + (size_t)(mBlock + m) * lda1;
      } else {
        arow = A2 + (size_t)(mBlock + m) * lda2;
      }
      av[i] = *(const float4*)(arow + kloc + kq);
    }
    if (WTR) {
#pragma unroll
      for (int i = 0; i < WVN; i++) {
        int c = tid + i * 256;           // BK k-rows x 8 n-quads
        int row = c >> 3, colq = c & 7;
        wv[i] = *(const float4*)(Wseg + (size_t)(kloc + row) * ldw + nBlock + colq * 4);
      }
    } else {
#pragma unroll
      for (int i = 0; i < WCH; i++) {
        int c = tid + i * 256;
        int n = c / KQ, kq = (c % KQ) * 4;
        wv[i] = *(const float4*)(Wseg + (size_t)(nBlock + n) * ldw + kloc + kq);
      }
    }
  };

  const int KT = K1 + K2;
  const int KS = KT / SPLIT;          // per-split K (multiple of BK; segment-aligned)
  const int kbeg = z * KS;
  const int NS = KS / BK;
  load_tile(kbeg);
  f32x4 acc[FM][FN] = {};

  for (int step = 0; step < NS; ++step) {
    __syncthreads();  // previous iteration's fragment reads done
    // commit regs -> LDS (f32 -> bf16, packed 8B stores)
#pragma unroll
    for (int i = 0; i < ACH; i++) {
      int c = tid + i * 256;
      int m = c / KQ, kq = (c % KQ) * 4;
      *(uint2*)&Al[m * LP + kq] = cvt4(av[i]);
    }
    if (WTR) {
#pragma unroll
      for (int i = 0; i < WVN; i++) {
        int c = tid + i * 256;
        int row = c >> 3, colq = c & 7;
        Wl[(colq * 4 + 0) * LP + row] = cvt1(wv[i].x);
        Wl[(colq * 4 + 1) * LP + row] = cvt1(wv[i].y);
        Wl[(colq * 4 + 2) * LP + row] = cvt1(wv[i].z);
        Wl[(colq * 4 + 3) * LP + row] = cvt1(wv[i].w);
      }
    } else {
#pragma unroll
      for (int i = 0; i < WCH; i++) {
        int c = tid + i * 256;
        int n = c / KQ, kq = (c % KQ) * 4;
        *(uint2*)&Wl[n * LP + kq] = cvt4(wv[i]);
      }
    }
    __syncthreads();

    if (step + 1 < NS) load_tile(kbeg + (step + 1) * BK);  // prefetch

    const int klane = (lane >> 4) << 3;
    const int r = lane & 15;
    short8 af[KSUB][FM], wf[KSUB][FN];
#pragma unroll
    for (int ks = 0; ks < KSUB; ks++) {
#pragma unroll
      for (int f = 0; f < FM; f++)
        af[ks][f] = *(const short8*)&Al[(wm + f * 16 + r) * LP + ks * 32 + klane];
#pragma unroll
      for (int f = 0; f < FN; f++)
        wf[ks][f] = *(const short8*)&Wl[(wn + f * 16 + r) * LP + ks * 32 + klane];
    }
#pragma unroll
    for (int ks = 0; ks < KSUB; ks++)
#pragma unroll
      for (int fm = 0; fm < FM; fm++)
#pragma unroll
        for (int fn = 0; fn < FN; fn++)
          acc[fm][fn] = __builtin_amdgcn_mfma_f32_16x16x32_bf16(
              af[ks][fm], wf[ks][fn], acc[fm][fn], 0, 0, 0);
  }

  // Epilogue. D layout: col = lane&15, row = (lane>>4)*4 + j
  float* Cp = C + (size_t)z * gridDim.y * BM * ldc;
  const int col = lane & 15, rb = (lane >> 4) << 2;
#pragma unroll
  for (int fn = 0; fn < FN; fn++) {
    int n = nBlock + wn + fn * 16 + col;
    float bsum = 0.f;
    if (z == 0) {
      if (bias1) bsum += bias1[n];
      if (bias2) bsum += bias2[n];
    }
#pragma unroll
    for (int fm = 0; fm < FM; fm++) {
#pragma unroll
      for (int j = 0; j < 4; j++) {
        int m = mBlock + wm + fm * 16 + rb + j;
        Cp[(size_t)m * ldc + n] = acc[fm][fn][j] + bsum;
      }
    }
  }
}

// ---------------------------------------------------------------------------
template <int P>
__global__ void lstm_pw(const float* __restrict__ Gp,
                        const float* __restrict__ c_prev,
                        float* __restrict__ h_out,
                        float* __restrict__ c_out) {
  int i4 = blockIdx.x * 256 + threadIdx.x;  // 32768 float4 slots (B*H/4)
  int b = i4 >> 8, j4 = i4 & 255;
  float4 gi{}, gf{}, gg{}, go{};
#pragma unroll
  for (int p = 0; p < P; p++) {
    const float4* g = (const float4*)(Gp + (size_t)p * Bv * 4 * Hv + (size_t)b * 4096);
    float4 a = g[j4], bb = g[256 + j4], c = g[512 + j4], d = g[768 + j4];
    gi.x += a.x; gi.y += a.y; gi.z += a.z; gi.w += a.w;
    gf.x += bb.x; gf.y += bb.y; gf.z += bb.z; gf.w += bb.w;
    gg.x += c.x; gg.y += c.y; gg.z += c.z; gg.w += c.w;
    go.x += d.x; go.y += d.y; go.z += d.z; go.w += d.w;
  }
  float4 c4 = ((const float4*)c_prev)[i4];
  float4 h4, cn4;
  float* gip = &gi.x; float* gfp = &gf.x; float* ggp = &gg.x; float* gop = &go.x;
  float* cp = &c4.x; float* hp = &h4.x; float* cnp = &cn4.x;
#pragma unroll
  for (int u = 0; u < 4; u++) {
    float si = 1.f / (1.f + expf(-gip[u]));
    float sf = 1.f / (1.f + expf(-gfp[u]));
    float so = 1.f / (1.f + expf(-gop[u]));
    float cn = sf * cp[u] + si * tanhf(ggp[u]);
    hp[u] = so * tanhf(cn);
    cnp[u] = cn;
  }
  ((float4*)h_out)[i4] = h4;
  ((float4*)c_out)[i4] = cn4;
}

// ---------------------------------------------------------------------------
// Fused attention pass 1, chunked for TLP. Grid (128 b, 16 chunks of 16 s),
// 2048 blocks (~8/CU). Per block: q[b] (sum of 4 split-K partials) -> LDS;
// 16 scores (4 wave-dots per wave, all row-loads independent); chunk-local
// max/exp/denominator; partial numerator over 16 rows with the whole block
// walking the SAME s-row per iteration (rows L2-hot from the score pass).
// enc is read from HBM exactly once across the grid; no sc roundtrip, no
// second 134 MB context pass. (R12 ran this at 512 blocks: latency-bound,
// 85 µs even fully L3-warm. TLP, not traffic, is the attention lever.)
__global__ __launch_bounds__(256) void attn_part(
    const float* __restrict__ enc, const float* __restrict__ qp,
    float* __restrict__ numb, float2* __restrict__ mden) {
  const int b = blockIdx.x, ch = blockIdx.y;
  const int t = threadIdx.x, lane = t & 63, wid = t >> 6;
  const int sbase = ch * 16;
  __shared__ float qs[1024];
  __shared__ float es[16], ee[16];
  {
    const float4* q0 = (const float4*)(qp + (size_t)b * Hv);
    const float4* q1 = (const float4*)(qp + 1 * Bv * Hv + (size_t)b * Hv);
    const float4* q2 = (const float4*)(qp + 2 * Bv * Hv + (size_t)b * Hv);
    const float4* q3 = (const float4*)(qp + 3 * Bv * Hv + (size_t)b * Hv);
    float4 a = q0[t], bq = q1[t], c = q2[t], d = q3[t];
    float4 s;
    s.x = a.x + bq.x + c.x + d.x; s.y = a.y + bq.y + c.y + d.y;
    s.z = a.z + bq.z + c.z + d.z; s.w = a.w + bq.w + c.w + d.w;
    ((float4*)qs)[t] = s;
  }
  __syncthreads();

  // scores: wave wid covers local s = wid*4 .. wid*4+3
  const float4* q4 = (const float4*)qs;
#pragma unroll
  for (int i = 0; i < 4; i++) {
    int sl = wid * 4 + i;
    const float4* e4 = (const float4*)(enc + ((size_t)(sbase + sl) * Bv + b) * Hv);
    float sum = 0.f;
#pragma unroll
    for (int j = 0; j < 4; j++) {
      int idx = lane + j * 64;
      float4 e = e4[idx], qq = q4[idx];
      sum += e.x * qq.x + e.y * qq.y + e.z * qq.z + e.w * qq.w;
    }
#pragma unroll
    for (int o = 32; o; o >>= 1) sum += __shfl_xor(sum, o);
    if (lane == 0) es[sl] = sum;
  }
  __syncthreads();

  // chunk-local softmax pieces
  float m = es[0];
#pragma unroll
  for (int i = 1; i < 16; i++) m = fmaxf(m, es[i]);
  if (t < 16) ee[t] = expf(es[t] - m);
  __syncthreads();
  if (t == 0) {
    float den = 0.f;
#pragma unroll
    for (int i = 0; i < 16; i++) den += ee[i];
    mden[b * 16 + ch] = make_float2(m, den);
  }

  // partial numerator: thread t owns h = t*4..+3; whole block walks the
  // same s-row together (4 KB coalesced per iteration, L2-hot rows).
  float4 acc = make_float4(0.f, 0.f, 0.f, 0.f);
  const float* ebase = enc + ((size_t)sbase * Bv + b) * Hv + t * 4;
#pragma unroll
  for (int s = 0; s < 16; s++) {
    float4 e = *(const float4*)(ebase + (size_t)s * Bv * Hv);
    float w = ee[s];
    acc.x += w * e.x; acc.y += w * e.y; acc.z += w * e.z; acc.w += w * e.w;
  }
  *(float4*)(numb + ((size_t)b * 16 + ch) * Hv + t * 4) = acc;
}

// ---------------------------------------------------------------------------
// Pass 2: exact recombination over the 16 chunks -> ctx.
__global__ __launch_bounds__(256) void attn_fin(
    const float* __restrict__ numb, const float2* __restrict__ mden,
    float* __restrict__ ctx) {
  const int b = blockIdx.x, t = threadIdx.x;
  float mv[16], dv[16];
  float M = -3.4e38f;
#pragma unroll
  for (int c = 0; c < 16; c++) {
    float2 md = mden[b * 16 + c];
    mv[c] = md.x; dv[c] = md.y;
    M = fmaxf(M, md.x);
  }
  float den = 0.f, sc[16];
#pragma unroll
  for (int c = 0; c < 16; c++) {
    sc[c] = expf(mv[c] - M);
    den += sc[c] * dv[c];
  }
  float inv = 1.f / den;
  float4 r = make_float4(0.f, 0.f, 0.f, 0.f);
#pragma unroll
  for (int c = 0; c < 16; c++) {
    float4 n = *(const float4*)(numb + ((size_t)b * 16 + c) * Hv + t * 4);
    float s = sc[c];
    r.x += s * n.x; r.y += s * n.y; r.z += s * n.z; r.w += s * n.w;
  }
  r.x *= inv; r.y *= inv; r.z *= inv; r.w *= inv;
  *(float4*)(ctx + (size_t)b * Hv + t * 4) = r;
}

// ---------------------------------------------------------------------------
__global__ void finish_cat(const float* __restrict__ catp,
                           float* __restrict__ cat) {
  int i4 = blockIdx.x * 256 + threadIdx.x;  // 32768 float4 slots
  constexpr int ST = Bv * Hv / 4;
  const float4* p = (const float4*)catp;
  float4 a = p[i4], b = p[ST + i4], c = p[2 * ST + i4], d = p[3 * ST + i4];
  float4 r;
  r.x = tanhf(a.x + b.x + c.x + d.x);
  r.y = tanhf(a.y + b.y + c.y + d.y);
  r.z = tanhf(a.z + b.z + c.z + d.z);
  r.w = tanhf(a.w + b.w + c.w + d.w);
  ((float4*)cat)[i4] = r;
}

// ---------------------------------------------------------------------------
extern "C" void kernel_launch(void* const* d_in, const int* in_sizes, int n_in,
                              void* d_out, int out_size, void* d_ws,
                              size_t ws_size, hipStream_t stream) {
  const int*   ids      = (const int*)d_in[0];
  const float* h0       = (const float*)d_in[1];
  const float* c0       = (const float*)d_in[2];
  const float* enc      = (const float*)d_in[3];
  const float* emb      = (const float*)d_in[4];
  const float* w_ih0    = (const float*)d_in[5];
  const float* w_hh0    = (const float*)d_in[6];
  const float* b_ih0    = (const float*)d_in[7];
  const float* b_hh0    = (const float*)d_in[8];
  const float* w_ih1    = (const float*)d_in[9];
  const float* w_hh1    = (const float*)d_in[10];
  const float* b_ih1    = (const float*)d_in[11];
  const float* b_hh1    = (const float*)d_in[12];
  const float* attn_w   = (const float*)d_in[13];
  const float* attn_b   = (const float*)d_in[14];  // cancels in softmax
  const float* concat_w = (const float*)d_in[15];
  const float* concat_b = (const float*)d_in[16];
  const float* out_w    = (const float*)d_in[17];
  const float* out_b    = (const float*)d_in[18];
  (void)attn_b;

  float* logits = (float*)d_out;                  // [128, 32000]
  float* hout   = logits + (size_t)Bv * Vv;       // [2, 128, 1024]
  float* cout   = hout + 2 * Bv * Hv;             // [2, 128, 1024]

  float* ws   = (float*)d_ws;
  float* G0p  = ws;                       // 3 * 524288 (dead after step 2)
  float* G1p  = G0p + 3 * 524288;         // 4 * 524288 (dead after step 4)
  float* qp   = G1p + 4 * (size_t)524288; // 4 * 131072
  float* catp = qp + 4 * 131072;          // 4 * 131072
  float* cat  = catp + 4 * 131072;        // 131072
  float* ctx  = cat + 131072;             // 131072
  float* numb = G1p;                      // 16*128*1024 = 2097152 (reuses G1p)
  float2* mden = (float2*)G0p;            // 2048 float2 (reuses G0p)

  const float* h_b = hout + Bv * Hv;  // layer-1 h (rnn_out)

  // 1. LSTM layer 0 gates: K = 512(emb,gathered) + 1024(h0), 3-way split-K
  gemm_mfma<64, 32, 64, 3, 0, 1, 4><<<dim3(128, 2, 3), 256, 0, stream>>>(
      ids, emb, Ev, Ev, h0, Hv, Hv, w_ih0, Ev, w_hh0, Hv, b_ih0, b_hh0,
      G0p, 4 * Hv, 4 * Hv);
  // 2. LSTM layer 0 pointwise (sums 3 partials); h -> hout[0]
  lstm_pw<3><<<128, 256, 0, stream>>>(G0p, c0, hout, cout);
  // 3. LSTM layer 1 gates: K = 1024(h_layer0) + 1024(h0[1]), 4-way split-K
  gemm_mfma<64, 32, 64, 4, 0, 0, 4><<<dim3(128, 2, 4), 256, 0, stream>>>(
      nullptr, hout, Hv, Hv, h0 + Bv * Hv, Hv, Hv, w_ih1, Hv, w_hh1, Hv,
      b_ih1, b_hh1, G1p, 4 * Hv, 4 * Hv);
  // 4. LSTM layer 1 pointwise (sums 4 partials)
  lstm_pw<4><<<128, 256, 0, stream>>>(G1p, c0 + Bv * Hv, hout + Bv * Hv,
                                      cout + Bv * Hv);
  // 5. q = rnn @ attn_w (transposed in staging), 4-way split-K
  gemm_mfma<64, 32, 64, 4, 1, 0, 4><<<dim3(32, 2, 4), 256, 0, stream>>>(
      nullptr, h_b, Hv, Hv, nullptr, 0, 0, attn_w, Hv,
      nullptr, 0, nullptr, nullptr, qp, Hv, Hv);
  // 6. fused scores+softmax-partials+partial-context, 2048 blocks (8/CU)
  attn_part<<<dim3(128, 16), 256, 0, stream>>>(enc, qp, numb, mden);
  // 7. exact chunk recombination -> ctx
  attn_fin<<<128, 256, 0, stream>>>(numb, mden, ctx);
  // 8. concat gates: K = 1024(rnn) + 1024(ctx), 4-way split-K
  gemm_mfma<64, 32, 64, 4, 0, 0, 4><<<dim3(32, 2, 4), 256, 0, stream>>>(
      nullptr, h_b, Hv, Hv, ctx, Hv, Hv, concat_w, 2 * Hv,
      concat_w + Hv, 2 * Hv, concat_b, nullptr, catp, Hv, Hv);
  // 9. cat = tanh(sum of partials)
  finish_cat<<<128, 256, 0, stream>>>(catp, cat);
  // 10. logits: BM=128/BN=128/BK=64, grid (250,1) -> out_w read exactly once
  gemm_mfma<128, 128, 64, 1, 0, 0, 1><<<dim3(250, 1, 1), 256, 0, stream>>>(
      nullptr, cat, Hv, Hv, nullptr, 0, 0, out_w, Hv, nullptr, 0,
      out_b, nullptr, logits, Vv, Vv);
}

// Round 15
// 149.449 us; speedup vs baseline: 2.7135x; 1.0093x over previous
//
#include <hip/hip_runtime.h>
#include <hip/hip_bf16.h>
#include <cstddef>
#include <cstdint>

// Problem dims
constexpr int Bv = 128;   // batch
constexpr int Sv = 256;   // src len
constexpr int Hv = 1024;  // hidden
constexpr int Ev = 512;   // embed
constexpr int Vv = 32000; // vocab

typedef __attribute__((ext_vector_type(4))) float f32x4;
typedef __attribute__((ext_vector_type(8))) short short8;

// f32x4 -> 4 packed bf16 (RNE), via v_cvt_pk_bf16_f32.
__device__ __forceinline__ uint2 cvt4(float4 v) {
  union { __hip_bfloat162 b; unsigned u; } lo, hi;
  lo.b = __float22bfloat162_rn(float2{v.x, v.y});
  hi.b = __float22bfloat162_rn(float2{v.z, v.w});
  uint2 r;
  r.x = lo.u;
  r.y = hi.u;
  return r;
}
__device__ __forceinline__ unsigned short cvt1(float x) {
  union { __hip_bfloat16 b; unsigned short u; } c;
  c.b = __float2bfloat16(x);
  return c.u;
}

// ---------------------------------------------------------------------------
// MFMA GEMM with split-K partials:
//   Cp[z][m,n] = sum_{k in split z} A[m,k]*W[n,k]  (+bias on z==0)
// A = A1 (k<K1, optionally gathered emb rows) then A2. W row-major [N,K]
// unless WTR (W1 is [K,N], transposed during LDS staging; needs BN==32).
// ABF16: A1 is bf16 row-major (pre-converted); loaded as uint2 (4 bf16)
//   per chunk with the SAME LDS commit addressing as the f32 path (no new
//   bank-conflict pattern -- R6's regression came from changed addressing).
// BK: K-tile per iteration. Bigger BK = more loads in flight per wave.
// Partial z written at C + z*gridDim.y*BM*ldc. Consumers sum partials.
// NOTE (R10 lesson): no cross-block atomics/fences — agent-scope ACQ_REL
// per block on 8-XCD forces L2 writeback storms (17x slowdown).
// ---------------------------------------------------------------------------
template <int BM, int BN, int BK, int SPLIT, int WTR, int GATHER, int ABF16,
          int MINW>
__global__ __launch_bounds__(256, MINW) void gemm_mfma(
    const int* __restrict__ ids,
    const float* __restrict__ A1, int lda1, int K1,
    const float* __restrict__ A2, int lda2, int K2,
    const float* __restrict__ W1, int ldw1,
    const float* __restrict__ W2, int ldw2,
    const float* __restrict__ bias1, const float* __restrict__ bias2,
    float* __restrict__ C, int ldc, int N) {
  constexpr int LP = BK + 8;       // LDS row pitch in bf16 (+8 pad)
  constexpr int KQ = BK / 4;       // 4-element chunks per row
  constexpr int KSUB = BK / 32;    // MFMA K-subtiles per iteration
  constexpr int WAVES_N = (BN >= 64) ? 2 : 1;
  constexpr int WAVES_M = 4 / WAVES_N;
  constexpr int WM = BM / WAVES_M;
  constexpr int FM = WM / 16;
  constexpr int FN = BN / (16 * WAVES_N);  // 32->2, 64->2, 128->4
  constexpr int WN = FN * 16;
  constexpr int ACH = (BM * BK) / (4 * 256);
  constexpr int WCH = (BN * BK) / (4 * 256);
  constexpr int WVN = WTR ? (BK * 8 / 256) : WCH;

  __shared__ unsigned short Al[BM * LP];
  __shared__ unsigned short Wl[BN * LP];

  const int tid = threadIdx.x;
  const int wid = tid >> 6, lane = tid & 63;
  const int nBlock = blockIdx.x * BN;
  const int mBlock = blockIdx.y * BM;
  const int z = blockIdx.z;
  int wm, wn;
  if (WAVES_N == 2) { wm = (wid >> 1) * WM; wn = (wid & 1) * WN; }
  else              { wm = wid * WM;        wn = 0; }

  float4 av[ABF16 ? 1 : ACH];
  uint2  ab[ABF16 ? ACH : 1];
  float4 wv[WVN];

  auto load_tile = [&](int kg) {
    const bool seg1 = kg < K1;
    const float* Wseg = seg1 ? W1 : W2;
    const int ldw = seg1 ? ldw1 : ldw2;
    const int kloc = seg1 ? kg : kg - K1;
    if (ABF16) {
      const unsigned short* Ab = (const unsigned short*)A1;
#pragma unroll
      for (int i = 0; i < ACH; i++) {
        int c = tid + i * 256;
        int m = c / KQ, kq = (c % KQ) * 4;
        ab[i] = *(const uint2*)(Ab + (size_t)(mBlock + m) * lda1 + kloc + kq);
      }
    } else {
#pragma unroll
      for (int i = 0; i < ACH; i++) {
        int c = tid + i * 256;
        int m = c / KQ, kq = (c % KQ) * 4;
        const float* arow;
        if (seg1) {
          if (GATHER) arow = A1 + (size_t)ids[mBlock + m] * lda1;
          else        arow = A1 + (size_t)(mBlock + m) * lda1;
        } else {
          arow = A2 + (size_t)(mBlock + m) * lda2;
        }
        av[i] = *(const float4*)(arow + kloc + kq);
      }
    }
    if (WTR) {
#pragma unroll
      for (int i = 0; i < WVN; i++) {
        int c = tid + i * 256;           // BK k-rows x 8 n-quads
        int row = c >> 3, colq = c & 7;
        wv[i] = *(const float4*)(Wseg + (size_t)(kloc + row) * ldw + nBlock + colq * 4);
      }
    } else {
#pragma unroll
      for (int i = 0; i < WCH; i++) {
        int c = tid + i * 256;
        int n = c / KQ, kq = (c % KQ) * 4;
        wv[i] = *(const float4*)(Wseg + (size_t)(nBlock + n) * ldw + kloc + kq);
      }
    }
  };

  const int KT = K1 + K2;
  const int KS = KT / SPLIT;          // per-split K (multiple of BK; segment-aligned)
  const int kbeg = z * KS;
  const int NS = KS / BK;
  load_tile(kbeg);
  f32x4 acc[FM][FN] = {};

  for (int step = 0; step < NS; ++step) {
    __syncthreads();  // previous iteration's fragment reads done
    // commit regs -> LDS (same uint2-per-chunk addressing in both paths)
#pragma unroll
    for (int i = 0; i < ACH; i++) {
      int c = tid + i * 256;
      int m = c / KQ, kq = (c % KQ) * 4;
      *(uint2*)&Al[m * LP + kq] = ABF16 ? ab[i] : cvt4(av[i]);
    }
    if (WTR) {
#pragma unroll
      for (int i = 0; i < WVN; i++) {
        int c = tid + i * 256;
        int row = c >> 3, colq = c & 7;
        Wl[(colq * 4 + 0) * LP + row] = cvt1(wv[i].x);
        Wl[(colq * 4 + 1) * LP + row] = cvt1(wv[i].y);
        Wl[(colq * 4 + 2) * LP + row] = cvt1(wv[i].z);
        Wl[(colq * 4 + 3) * LP + row] = cvt1(wv[i].w);
      }
    } else {
#pragma unroll
      for (int i = 0; i < WCH; i++) {
        int c = tid + i * 256;
        int n = c / KQ, kq = (c % KQ) * 4;
        *(uint2*)&Wl[n * LP + kq] = cvt4(wv[i]);
      }
    }
    __syncthreads();

    if (step + 1 < NS) load_tile(kbeg + (step + 1) * BK);  // prefetch

    const int klane = (lane >> 4) << 3;
    const int r = lane & 15;
    short8 af[KSUB][FM], wf[KSUB][FN];
#pragma unroll
    for (int ks = 0; ks < KSUB; ks++) {
#pragma unroll
      for (int f = 0; f < FM; f++)
        af[ks][f] = *(const short8*)&Al[(wm + f * 16 + r) * LP + ks * 32 + klane];
#pragma unroll
      for (int f = 0; f < FN; f++)
        wf[ks][f] = *(const short8*)&Wl[(wn + f * 16 + r) * LP + ks * 32 + klane];
    }
#pragma unroll
    for (int ks = 0; ks < KSUB; ks++)
#pragma unroll
      for (int fm = 0; fm < FM; fm++)
#pragma unroll
        for (int fn = 0; fn < FN; fn++)
          acc[fm][fn] = __builtin_amdgcn_mfma_f32_16x16x32_bf16(
              af[ks][fm], wf[ks][fn], acc[fm][fn], 0, 0, 0);
  }

  // Epilogue. D layout: col = lane&15, row = (lane>>4)*4 + j
  float* Cp = C + (size_t)z * gridDim.y * BM * ldc;
  const int col = lane & 15, rb = (lane >> 4) << 2;
#pragma unroll
  for (int fn = 0; fn < FN; fn++) {
    int n = nBlock + wn + fn * 16 + col;
    float bsum = 0.f;
    if (z == 0) {
      if (bias1) bsum += bias1[n];
      if (bias2) bsum += bias2[n];
    }
#pragma unroll
    for (int fm = 0; fm < FM; fm++) {
#pragma unroll
      for (int j = 0; j < 4; j++) {
        int m = mBlock + wm + fm * 16 + rb + j;
        Cp[(size_t)m * ldc + n] = acc[fm][fn][j] + bsum;
      }
    }
  }
}

// ---------------------------------------------------------------------------
template <int P>
__global__ void lstm_pw(const float* __restrict__ Gp,
                        const float* __restrict__ c_prev,
                        float* __restrict__ h_out,
                        float* __restrict__ c_out) {
  int i4 = blockIdx.x * 256 + threadIdx.x;  // 32768 float4 slots (B*H/4)
  int b = i4 >> 8, j4 = i4 & 255;
  float4 gi{}, gf{}, gg{}, go{};
#pragma unroll
  for (int p = 0; p < P; p++) {
    const float4* g = (const float4*)(Gp + (size_t)p * Bv * 4 * Hv + (size_t)b * 4096);
    float4 a = g[j4], bb = g[256 + j4], c = g[512 + j4], d = g[768 + j4];
    gi.x += a.x; gi.y += a.y; gi.z += a.z; gi.w += a.w;
    gf.x += bb.x; gf.y += bb.y; gf.z += bb.z; gf.w += bb.w;
    gg.x += c.x; gg.y += c.y; gg.z += c.z; gg.w += c.w;
    go.x += d.x; go.y += d.y; go.z += d.z; go.w += d.w;
  }
  float4 c4 = ((const float4*)c_prev)[i4];
  float4 h4, cn4;
  float* gip = &gi.x; float* gfp = &gf.x; float* ggp = &gg.x; float* gop = &go.x;
  float* cp = &c4.x; float* hp = &h4.x; float* cnp = &cn4.x;
#pragma unroll
  for (int u = 0; u < 4; u++) {
    float si = 1.f / (1.f + expf(-gip[u]));
    float sf = 1.f / (1.f + expf(-gfp[u]));
    float so = 1.f / (1.f + expf(-gop[u]));
    float cn = sf * cp[u] + si * tanhf(ggp[u]);
    hp[u] = so * tanhf(cn);
    cnp[u] = cn;
  }
  ((float4*)h_out)[i4] = h4;
  ((float4*)c_out)[i4] = cn4;
}

// ---------------------------------------------------------------------------
// Fused attention pass 1, chunked for TLP. Grid (128 b, 16 chunks of 16 s),
// 2048 blocks (~8/CU). Per block: q[b] (sum of 4 split-K partials) -> LDS;
// 16 scores (4 wave-dots per wave); chunk-local max/exp/denominator;
// partial numerator over 16 rows, whole block on the same s-row (L2-hot).
// enc read from HBM exactly once across the grid.
__global__ __launch_bounds__(256) void attn_part(
    const float* __restrict__ enc, const float* __restrict__ qp,
    float* __restrict__ numb, float2* __restrict__ mden) {
  const int b = blockIdx.x, ch = blockIdx.y;
  const int t = threadIdx.x, lane = t & 63, wid = t >> 6;
  const int sbase = ch * 16;
  __shared__ float qs[1024];
  __shared__ float es[16], ee[16];
  {
    const float4* q0 = (const float4*)(qp + (size_t)b * Hv);
    const float4* q1 = (const float4*)(qp + 1 * Bv * Hv + (size_t)b * Hv);
    const float4* q2 = (const float4*)(qp + 2 * Bv * Hv + (size_t)b * Hv);
    const float4* q3 = (const float4*)(qp + 3 * Bv * Hv + (size_t)b * Hv);
    float4 a = q0[t], bq = q1[t], c = q2[t], d = q3[t];
    float4 s;
    s.x = a.x + bq.x + c.x + d.x; s.y = a.y + bq.y + c.y + d.y;
    s.z = a.z + bq.z + c.z + d.z; s.w = a.w + bq.w + c.w + d.w;
    ((float4*)qs)[t] = s;
  }
  __syncthreads();

  // scores: wave wid covers local s = wid*4 .. wid*4+3
  const float4* q4 = (const float4*)qs;
#pragma unroll
  for (int i = 0; i < 4; i++) {
    int sl = wid * 4 + i;
    const float4* e4 = (const float4*)(enc + ((size_t)(sbase + sl) * Bv + b) * Hv);
    float sum = 0.f;
#pragma unroll
    for (int j = 0; j < 4; j++) {
      int idx = lane + j * 64;
      float4 e = e4[idx], qq = q4[idx];
      sum += e.x * qq.x + e.y * qq.y + e.z * qq.z + e.w * qq.w;
    }
#pragma unroll
    for (int o = 32; o; o >>= 1) sum += __shfl_xor(sum, o);
    if (lane == 0) es[sl] = sum;
  }
  __syncthreads();

  // chunk-local softmax pieces
  float m = es[0];
#pragma unroll
  for (int i = 1; i < 16; i++) m = fmaxf(m, es[i]);
  if (t < 16) ee[t] = expf(es[t] - m);
  __syncthreads();
  if (t == 0) {
    float den = 0.f;
#pragma unroll
    for (int i = 0; i < 16; i++) den += ee[i];
    mden[b * 16 + ch] = make_float2(m, den);
  }

  // partial numerator: thread t owns h = t*4..+3; whole block walks the
  // same s-row together (4 KB coalesced per iteration, L2-hot rows).
  float4 acc = make_float4(0.f, 0.f, 0.f, 0.f);
  const float* ebase = enc + ((size_t)sbase * Bv + b) * Hv + t * 4;
#pragma unroll
  for (int s = 0; s < 16; s++) {
    float4 e = *(const float4*)(ebase + (size_t)s * Bv * Hv);
    float w = ee[s];
    acc.x += w * e.x; acc.y += w * e.y; acc.z += w * e.z; acc.w += w * e.w;
  }
  *(float4*)(numb + ((size_t)b * 16 + ch) * Hv + t * 4) = acc;
}

// ---------------------------------------------------------------------------
// Pass 2: exact recombination over the 16 chunks -> ctx.
__global__ __launch_bounds__(256) void attn_fin(
    const float* __restrict__ numb, const float2* __restrict__ mden,
    float* __restrict__ ctx) {
  const int b = blockIdx.x, t = threadIdx.x;
  float mv[16], dv[16];
  float M = -3.4e38f;
#pragma unroll
  for (int c = 0; c < 16; c++) {
    float2 md = mden[b * 16 + c];
    mv[c] = md.x; dv[c] = md.y;
    M = fmaxf(M, md.x);
  }
  float den = 0.f, sc[16];
#pragma unroll
  for (int c = 0; c < 16; c++) {
    sc[c] = expf(mv[c] - M);
    den += sc[c] * dv[c];
  }
  float inv = 1.f / den;
  float4 r = make_float4(0.f, 0.f, 0.f, 0.f);
#pragma unroll
  for (int c = 0; c < 16; c++) {
    float4 n = *(const float4*)(numb + ((size_t)b * 16 + c) * Hv + t * 4);
    float s = sc[c];
    r.x += s * n.x; r.y += s * n.y; r.z += s * n.z; r.w += s * n.w;
  }
  r.x *= inv; r.y *= inv; r.z *= inv; r.w *= inv;
  *(float4*)(ctx + (size_t)b * Hv + t * 4) = r;
}

// ---------------------------------------------------------------------------
// cat = tanh(sum of 4 partials), stored bf16 (sole consumer is the logits
// GEMM, which converted to bf16 anyway -- bit-identical, halves A traffic).
__global__ void finish_cat(const float* __restrict__ catp,
                           unsigned short* __restrict__ catb) {
  int i4 = blockIdx.x * 256 + threadIdx.x;  // 32768 slots of 4
  constexpr int ST = Bv * Hv / 4;
  const float4* p = (const float4*)catp;
  float4 a = p[i4], b = p[ST + i4], c = p[2 * ST + i4], d = p[3 * ST + i4];
  float4 r;
  r.x = tanhf(a.x + b.x + c.x + d.x);
  r.y = tanhf(a.y + b.y + c.y + d.y);
  r.z = tanhf(a.z + b.z + c.z + d.z);
  r.w = tanhf(a.w + b.w + c.w + d.w);
  *(uint2*)&catb[(size_t)i4 * 4] = cvt4(r);
}

// ---------------------------------------------------------------------------
extern "C" void kernel_launch(void* const* d_in, const int* in_sizes, int n_in,
                              void* d_out, int out_size, void* d_ws,
                              size_t ws_size, hipStream_t stream) {
  const int*   ids      = (const int*)d_in[0];
  const float* h0       = (const float*)d_in[1];
  const float* c0       = (const float*)d_in[2];
  const float* enc      = (const float*)d_in[3];
  const float* emb      = (const float*)d_in[4];
  const float* w_ih0    = (const float*)d_in[5];
  const float* w_hh0    = (const float*)d_in[6];
  const float* b_ih0    = (const float*)d_in[7];
  const float* b_hh0    = (const float*)d_in[8];
  const float* w_ih1    = (const float*)d_in[9];
  const float* w_hh1    = (const float*)d_in[10];
  const float* b_ih1    = (const float*)d_in[11];
  const float* b_hh1    = (const float*)d_in[12];
  const float* attn_w   = (const float*)d_in[13];
  const float* attn_b   = (const float*)d_in[14];  // cancels in softmax
  const float* concat_w = (const float*)d_in[15];
  const float* concat_b = (const float*)d_in[16];
  const float* out_w    = (const float*)d_in[17];
  const float* out_b    = (const float*)d_in[18];
  (void)attn_b;

  float* logits = (float*)d_out;                  // [128, 32000]
  float* hout   = logits + (size_t)Bv * Vv;       // [2, 128, 1024]
  float* cout   = hout + 2 * Bv * Hv;             // [2, 128, 1024]

  float* ws   = (float*)d_ws;
  float* G0p  = ws;                       // 3 * 524288 (dead after step 2)
  float* G1p  = G0p + 3 * 524288;         // 4 * 524288 (dead after step 4)
  float* qp   = G1p + 4 * (size_t)524288; // 4 * 131072
  float* catp = qp + 4 * 131072;          // 4 * 131072
  float* ctx  = catp + 4 * 131072;        // 131072
  unsigned short* catb = (unsigned short*)(ctx + 131072);  // 131072 bf16
  float* numb = G1p;                      // 16*128*1024 = 2097152 (reuses G1p)
  float2* mden = (float2*)G0p;            // 2048 float2 (reuses G0p)

  const float* h_b = hout + Bv * Hv;  // layer-1 h (rnn_out)

  // 1. LSTM layer 0 gates: K = 512(emb,gathered) + 1024(h0), 3-way split-K
  gemm_mfma<64, 32, 64, 3, 0, 1, 0, 4><<<dim3(128, 2, 3), 256, 0, stream>>>(
      ids, emb, Ev, Ev, h0, Hv, Hv, w_ih0, Ev, w_hh0, Hv, b_ih0, b_hh0,
      G0p, 4 * Hv, 4 * Hv);
  // 2. LSTM layer 0 pointwise (sums 3 partials); h -> hout[0]
  lstm_pw<3><<<128, 256, 0, stream>>>(G0p, c0, hout, cout);
  // 3. LSTM layer 1 gates: K = 1024(h_layer0) + 1024(h0[1]), 4-way split-K
  gemm_mfma<64, 32, 64, 4, 0, 0, 0, 4><<<dim3(128, 2, 4), 256, 0, stream>>>(
      nullptr, hout, Hv, Hv, h0 + Bv * Hv, Hv, Hv, w_ih1, Hv, w_hh1, Hv,
      b_ih1, b_hh1, G1p, 4 * Hv, 4 * Hv);
  // 4. LSTM layer 1 pointwise (sums 4 partials)
  lstm_pw<4><<<128, 256, 0, stream>>>(G1p, c0 + Bv * Hv, hout + Bv * Hv,
                                      cout + Bv * Hv);
  // 5. q = rnn @ attn_w (transposed in staging), 4-way split-K
  gemm_mfma<64, 32, 64, 4, 1, 0, 0, 4><<<dim3(32, 2, 4), 256, 0, stream>>>(
      nullptr, h_b, Hv, Hv, nullptr, 0, 0, attn_w, Hv,
      nullptr, 0, nullptr, nullptr, qp, Hv, Hv);
  // 6. fused scores+softmax-partials+partial-context, 2048 blocks (8/CU)
  attn_part<<<dim3(128, 16), 256, 0, stream>>>(enc, qp, numb, mden);
  // 7. exact chunk recombination -> ctx
  attn_fin<<<128, 256, 0, stream>>>(numb, mden, ctx);
  // 8. concat gates: K = 1024(rnn) + 1024(ctx), 4-way split-K
  gemm_mfma<64, 32, 64, 4, 0, 0, 0, 4><<<dim3(32, 2, 4), 256, 0, stream>>>(
      nullptr, h_b, Hv, Hv, ctx, Hv, Hv, concat_w, 2 * Hv,
      concat_w + Hv, 2 * Hv, concat_b, nullptr, catp, Hv, Hv);
  // 9. cat = tanh(sum of partials) -> bf16 (bit-identical to GEMM's cvt)
  finish_cat<<<128, 256, 0, stream>>>(catp, catb);
  // 10. logits: BM=128/BN=128/BK=64, grid (250,1), out_w read exactly once;
  //     A is bf16 (halves the 128 MB L2/L3 A-stream, drops staging cvt).
  gemm_mfma<128, 128, 64, 1, 0, 0, 1, 1><<<dim3(250, 1, 1), 256, 0, stream>>>(
      nullptr, (const float*)catb, Hv, Hv, nullptr, 0, 0, out_w, Hv,
      nullptr, 0, out_b, nullptr, logits, Vv, Vv);
}